// Round 10
// baseline (9655.153 us; speedup 1.0000x reference)
//
#include <hip/hip_runtime.h>
#include <stdint.h>
#include <stddef.h>

#define B_  64
#define T_  256
#define H_  1024
#define AS_ 128
#define L_  3

typedef __attribute__((ext_vector_type(8))) short bf16x8;
typedef __attribute__((ext_vector_type(4))) float f32x4;

__device__ __forceinline__ unsigned short f2bf(float f) {
  union { float f; unsigned u; } x; x.f = f;
  unsigned r = x.u + 0x7fffu + ((x.u >> 16) & 1u);   // RNE
  return (unsigned short)(r >> 16);
}
__device__ __forceinline__ float bf2f(unsigned short s) {
  union { unsigned u; float f; } x; x.u = ((unsigned)s) << 16; return x.f;
}
__device__ __forceinline__ float sigmf(float x) { return 1.0f / (1.0f + __expf(-x)); }
__device__ __forceinline__ float tanh_f(float x) {
  x = fminf(fmaxf(x, -15.0f), 15.0f);
  float e = __expf(2.0f * x);
  return (e - 1.0f) / (e + 1.0f);
}

// ---- device-coherent (MALL) accessors: relaxed agent atomics — proven R2/R5/R8/R9 ----
__device__ __forceinline__ unsigned long long ld_u64_cc(const void* p) {
  return __hip_atomic_load((const unsigned long long*)p, __ATOMIC_RELAXED, __HIP_MEMORY_SCOPE_AGENT);
}
__device__ __forceinline__ void st_u16_cc(unsigned short* p, unsigned short v) {
  __hip_atomic_store(p, v, __ATOMIC_RELAXED, __HIP_MEMORY_SCOPE_AGENT);
}
__device__ __forceinline__ void st_u32_cc(unsigned* p, unsigned v) {
  __hip_atomic_store(p, v, __ATOMIC_RELAXED, __HIP_MEMORY_SCOPE_AGENT);
}
__device__ __forceinline__ unsigned ld_u32_cc(const unsigned* p) {
  return __hip_atomic_load(p, __ATOMIC_RELAXED, __HIP_MEMORY_SCOPE_AGENT);
}

// ---------------- tiny utility kernels ----------------

__global__ void k_zero(unsigned* p, int n) {
  int i = blockIdx.x * 256 + threadIdx.x;
  if (i < n) st_u32_cc(p + i, 0u);
}

__global__ void k_wt_i2h(const float* __restrict__ W, const float* __restrict__ b,
                         unsigned short* __restrict__ Wt) {
  int id = blockIdx.x * 256 + threadIdx.x;
  if (id >= AS_ * H_) return;
  int a = id >> 10, h = id & 1023;
  Wt[id] = f2bf(W[h * AS_ + a] + b[h]);
}

__global__ void k_f2b(const float* __restrict__ s, unsigned short* __restrict__ d, int n) {
  int i = blockIdx.x * 256 + threadIdx.x;
  if (i < n) d[i] = f2bf(s[i]);
}

__global__ void k_bias(const float* __restrict__ bi, const float* __restrict__ bh,
                       float* __restrict__ o, int n) {
  int i = blockIdx.x * 256 + threadIdx.x;
  if (i < n) o[i] = bi[i] + bh[i];
}

__global__ __launch_bounds__(128) void k_gather(const float* __restrict__ seq,
                                                const unsigned short* __restrict__ Wt,
                                                unsigned short* __restrict__ xbf) {
  __shared__ int sidx;
  const int bt = blockIdx.x, tid = threadIdx.x;
  if (seq[(size_t)bt * AS_ + tid] > 0.5f) sidx = tid;
  __syncthreads();
  const uint4* s = (const uint4*)(Wt + (size_t)sidx * H_);
  uint4* d = (uint4*)(xbf + (size_t)bt * H_);
  d[tid] = s[tid];
}

// ---------------- MFMA GEMM ----------------
// OUT==0: float row-major [M][N].  OUT==2: bf16 scan-native (uu=64) layout:
// idx = (((tt*4 + gb)*16 + ug) << 12) | (b_local<<8) | (u_local<<2) | gate
// from row = b*256+t (M=B*T), col = gate*1024+u (N=4096); ug=u>>6, u_local=u&63.

__device__ __forceinline__ void gld16(const void* g, void* l) {
  __builtin_amdgcn_global_load_lds((const __attribute__((address_space(1))) unsigned int*)g,
                                   (__attribute__((address_space(3))) unsigned int*)l,
                                   16, 0, 0);
}

template <int OUT>
__global__ __launch_bounds__(256) void k_gemm(const unsigned short* __restrict__ A,
                                              const unsigned short* __restrict__ Bm,
                                              const float* __restrict__ bias,
                                              void* __restrict__ Cout,
                                              int M, int N, int K) {
  __shared__ __align__(16) unsigned short As[128 * 32];
  __shared__ __align__(16) unsigned short Bs[128 * 32];
  const int tid = threadIdx.x, lane = tid & 63, wv = tid >> 6;
  const int m0 = blockIdx.x * 128, n0 = blockIdx.y * 128;
  const int wr = wv >> 1, wc = wv & 1;
  const int kg = lane >> 4, li = lane & 15;
  f32x4 acc[4][4] = {};

  for (int k0 = 0; k0 < K; k0 += 32) {
    for (int i = 0; i < 2; ++i) {
      int c0 = i * 256 + wv * 64;
      int cid = c0 + lane;
      int row = cid >> 2, lc = cid & 3;
      int sc = lc ^ ((row >> 1) & 3);
      gld16(A + (size_t)(m0 + row) * K + k0 + sc * 8, (char*)As + (size_t)c0 * 16);
      gld16(Bm + (size_t)(n0 + row) * K + k0 + sc * 8, (char*)Bs + (size_t)c0 * 16);
    }
    __syncthreads();
    bf16x8 af[4], bfm[4];
#pragma unroll
    for (int mi = 0; mi < 4; ++mi) {
      int row = wr * 64 + mi * 16 + li;
      int pc = kg ^ ((row >> 1) & 3);
      af[mi] = *(const bf16x8*)((const char*)As + row * 64 + pc * 16);
    }
#pragma unroll
    for (int ni = 0; ni < 4; ++ni) {
      int row = wc * 64 + ni * 16 + li;
      int pc = kg ^ ((row >> 1) & 3);
      bfm[ni] = *(const bf16x8*)((const char*)Bs + row * 64 + pc * 16);
    }
#pragma unroll
    for (int mi = 0; mi < 4; ++mi)
#pragma unroll
      for (int ni = 0; ni < 4; ++ni)
        acc[mi][ni] = __builtin_amdgcn_mfma_f32_16x16x32_bf16(af[mi], bfm[ni], acc[mi][ni], 0, 0, 0);
    __syncthreads();
  }

#pragma unroll
  for (int mi = 0; mi < 4; ++mi)
#pragma unroll
    for (int ni = 0; ni < 4; ++ni)
#pragma unroll
      for (int r = 0; r < 4; ++r) {
        int row = m0 + wr * 64 + mi * 16 + kg * 4 + r;
        int col = n0 + wc * 64 + ni * 16 + li;
        float v = acc[mi][ni][r] + bias[col];
        if (OUT == 0) {
          ((float*)Cout)[(size_t)row * N + col] = v;
        } else {
          int b = row >> 8, tt = row & 255;
          int g = col >> 10, u = col & 1023;
          int idx = (((tt * 4 + (b >> 4)) * 16 + (u >> 6)) << 12) |
                    ((b & 15) << 8) | ((u & 63) << 2) | g;
          ((unsigned short*)Cout)[idx] = f2bf(v);
        }
      }
}

// ---------------- persistent LSTM scan: uu=64, ALL weights in VGPRs ----------------
// 64 wgs x 512 threads: wg = (gb in [0,4), ug in [0,16)) owns batches [gb*16,+16)
// x units [ug*64,+64). 256 weight rows (r = u_local*4+gate): wave w holds rows
// [w*32,+32) as afr0/afr1 (256 VGPRs/lane, loop-invariant, static-indexed).
// LDS = 32KB h-stage only. Per step: poll 16 slots (64B line) -> ONE untagged
// bulk read 32KB/wg (2 MB/step total) -> LDS -> 64 MFMA/wave (one B-frag read
// feeds both afr blocks) -> lane-local update (2 units x 4 gates) -> publish
// + drain -> slot. Overwrite safety: slot>=t+1 for all => parity consumed.

__global__ __launch_bounds__(512, 1) void k_scan(
    const unsigned short* __restrict__ xgs,   // scan-native (see k_gemm OUT=2)
    const float* __restrict__ Whh,            // [4H][H] f32
    unsigned short* __restrict__ h_pp,        // [2][B][H] bf16 (MALL)
    unsigned short* __restrict__ out_seq,     // [B*T][H] bf16 or null
    float* __restrict__ hT, float* __restrict__ cT,
    const float* __restrict__ h0, const float* __restrict__ c0,
    unsigned* __restrict__ slots) {           // [4][16] this layer
  __shared__ __align__(16) unsigned short Hs[16 * 1024];     // 32 KB
  const int tid = threadIdx.x, lane = tid & 63, w = tid >> 6;   // 8 waves
  const int gb = blockIdx.x >> 4, ug = blockIdx.x & 15;
  const int li = lane & 15, kq = lane >> 4;
  const int b  = gb * 16 + li;
  const int u0 = ug * 64 + w * 8 + kq;        // acc0's unit
  const int u1 = u0 + 4;                      // acc1's unit

  // ---- publish h0 (read parity 1 at t=0); settles during weight load
  st_u16_cc(&h_pp[((size_t)B_ + b) * H_ + u0], f2bf(h0[(size_t)b * H_ + u0]));
  st_u16_cc(&h_pp[((size_t)B_ + b) * H_ + u1], f2bf(h0[(size_t)b * H_ + u1]));

  // ---- ALL weights -> VGPRs: wave w holds A-rows [w*32,+16) (afr0) and [+16,+32) (afr1)
  bf16x8 afr0[32], afr1[32];
  {
    const int r0 = w * 32 + li;               // gate = r0&3, u_local = r0>>2
    const float* wr0 = Whh + ((size_t)(r0 & 3) * H_ + ug * 64 + (r0 >> 2)) * H_ + kq * 8;
    const float* wr1 = wr0 + 4 * H_ * 0 + ((size_t)4) * H_;  // r1 = r0+16 -> same gate, u_local+4
#pragma unroll
    for (int ks = 0; ks < 32; ++ks) {
      const float4 f0 = *(const float4*)(wr0 + ks * 32);
      const float4 f1 = *(const float4*)(wr0 + ks * 32 + 4);
      union { ushort4 a[2]; bf16x8 v; } p0;
      p0.a[0] = ushort4{f2bf(f0.x), f2bf(f0.y), f2bf(f0.z), f2bf(f0.w)};
      p0.a[1] = ushort4{f2bf(f1.x), f2bf(f1.y), f2bf(f1.z), f2bf(f1.w)};
      afr0[ks] = p0.v;
      const float4 g0 = *(const float4*)(wr1 + ks * 32);
      const float4 g1 = *(const float4*)(wr1 + ks * 32 + 4);
      union { ushort4 a[2]; bf16x8 v; } p1;
      p1.a[0] = ushort4{f2bf(g0.x), f2bf(g0.y), f2bf(g0.z), f2bf(g0.w)};
      p1.a[1] = ushort4{f2bf(g1.x), f2bf(g1.y), f2bf(g1.z), f2bf(g1.w)};
      afr1[ks] = p1.v;
    }
  }
  float cs0 = c0[(size_t)b * H_ + u0], cs1 = c0[(size_t)b * H_ + u1];
  __syncthreads();                            // drains h0 publishes (per-wave vmcnt0)
  unsigned* slmy = slots + gb * 16 + ug;
  const unsigned* sl = slots + gb * 16;
  if (tid == 0) {
    st_u32_cc(slmy, 1u);
    asm volatile("s_waitcnt vmcnt(0)" ::: "memory");
  }

  const char* hbase = (const char*)Hs + (size_t)li * 2048;
  const int fxor = (li & 7) << 4;
  const int sb = tid >> 5, seg = tid & 31;    // stage: batch row sb, 64B segment seg
  const int sswz = (sb & 7) << 4;
  char* drow = (char*)Hs + (size_t)sb * 2048;

  for (int t = 0; t < T_; ++t) {
    // ---- poll 16 slots (one 64B coalesced read per pass)
    if (w == 0) {
      const unsigned tgt = (unsigned)(t + 1);
      unsigned v;
      do {
        __builtin_amdgcn_s_sleep(1);
        v = ld_u32_cc(&sl[lane & 15]);
      } while (__any((int)(v < tgt)));
    }
    __syncthreads();

    // ---- ONE untagged bulk read (8 u64/thread, rotated) -> LDS swizzled
    {
      const char* src = (const char*)(h_pp + (size_t)((t & 1) ^ 1) * (B_ * H_) +
                                      (size_t)(gb * 16 + sb) * H_) + seg * 64;
      unsigned long long wb[8];
#pragma unroll
      for (int p = 0; p < 8; ++p) wb[p] = ld_u64_cc(src + ((p + seg) & 7) * 8);
#pragma unroll
      for (int p = 0; p < 8; ++p) {
        const int c = (p + seg) & 7;
        *(unsigned long long*)(drow + ((seg * 64 + c * 8) ^ sswz)) = wb[p];
      }
    }
    // ---- xv: two u64 (4 gates each for u0,u1), coalesced scan-native layout
    const size_t xb2 = ((((size_t)(t * 4 + gb) * 16 + ug) << 12) |
                        (li << 8) | ((w * 8 + kq) << 2)) * 2;
    const ushort4 xa = *(const ushort4*)((const char*)xgs + xb2);
    const ushort4 xb = *(const ushort4*)((const char*)xgs + xb2 + 32);
    __syncthreads();                          // Hs staged

    // ---- MFMA: one h B-frag feeds both reg-A blocks
    f32x4 a0 = {0.f, 0.f, 0.f, 0.f}, a1 = {0.f, 0.f, 0.f, 0.f};
#pragma unroll
    for (int ks = 0; ks < 32; ++ks) {
      const bf16x8 bb = *(const bf16x8*)(hbase + ((ks * 64 + kq * 16) ^ fxor));
      a0 = __builtin_amdgcn_mfma_f32_16x16x32_bf16(afr0[ks], bb, a0, 0, 0, 0);
      a1 = __builtin_amdgcn_mfma_f32_16x16x32_bf16(afr1[ks], bb, a1, 0, 0, 0);
    }

    // ---- lane-local cell update (2 units x 4 gates)
    float h0v, h1v;
    {
      float gi = a0[0] + bf2f(xa.x), gf = a0[1] + bf2f(xa.y);
      float gg = a0[2] + bf2f(xa.z), go = a0[3] + bf2f(xa.w);
      float ci = sigmf(gf) * cs0 + sigmf(gi) * tanh_f(gg);
      cs0 = ci; h0v = sigmf(go) * tanh_f(ci);
    }
    {
      float gi = a1[0] + bf2f(xb.x), gf = a1[1] + bf2f(xb.y);
      float gg = a1[2] + bf2f(xb.z), go = a1[3] + bf2f(xb.w);
      float ci = sigmf(gf) * cs1 + sigmf(gi) * tanh_f(gg);
      cs1 = ci; h1v = sigmf(go) * tanh_f(ci);
    }
    const unsigned short hb0 = f2bf(h0v), hb1 = f2bf(h1v);
    if (out_seq) {
      out_seq[((size_t)b * T_ + t) * H_ + u0] = hb0;
      out_seq[((size_t)b * T_ + t) * H_ + u1] = hb1;
    }
    if (t < T_ - 1) {
      st_u16_cc(&h_pp[((size_t)(t & 1) * B_ + b) * H_ + u0], hb0);
      st_u16_cc(&h_pp[((size_t)(t & 1) * B_ + b) * H_ + u1], hb1);
      __syncthreads();                        // all waves' publishes drained
      if (tid == 0) {
        st_u32_cc(slmy, (unsigned)(t + 2));
        asm volatile("s_waitcnt vmcnt(0)" ::: "memory");
      }
    } else {
      hT[(size_t)b * H_ + u0] = h0v; hT[(size_t)b * H_ + u1] = h1v;
      cT[(size_t)b * H_ + u0] = cs0; cT[(size_t)b * H_ + u1] = cs1;
    }
  }
}

// ---------------- launcher ----------------

extern "C" void kernel_launch(void* const* d_in, const int* in_sizes, int n_in,
                              void* d_out, int out_size, void* d_ws, size_t ws_size,
                              hipStream_t stream) {
  const float* seq  = (const float*)d_in[0];
  const float* Wi2h = (const float*)d_in[1];
  const float* bi2h = (const float*)d_in[2];
  const float* Wih  = (const float*)d_in[3];
  const float* Whh  = (const float*)d_in[4];
  const float* bih  = (const float*)d_in[5];
  const float* bhh  = (const float*)d_in[6];
  const float* Wh2o = (const float*)d_in[7];
  const float* bh2o = (const float*)d_in[8];
  const float* h0   = (const float*)d_in[9];
  const float* c0   = (const float*)d_in[10];
  float* outF = (float*)d_out;

  size_t off = 0;
  auto nb = [&](size_t bytes) { size_t r = off; off += (bytes + 255) & ~(size_t)255; return r; };
  unsigned short* xbf   = (unsigned short*)((char*)d_ws + nb((size_t)B_ * T_ * H_ * 2));
  unsigned short* seqA  = (unsigned short*)((char*)d_ws + nb((size_t)B_ * T_ * H_ * 2));
  unsigned short* xgs   = (unsigned short*)((char*)d_ws + nb((size_t)B_ * T_ * 4 * H_ * 2));
  unsigned short* Wihb  = (unsigned short*)((char*)d_ws + nb((size_t)L_ * 4 * H_ * H_ * 2));
  unsigned short* Wh2ob = (unsigned short*)((char*)d_ws + nb((size_t)AS_ * H_ * 2));
  unsigned short* Wt    = (unsigned short*)((char*)d_ws + nb((size_t)AS_ * H_ * 2));
  float*          bsum  = (float*)((char*)d_ws + nb((size_t)L_ * 4 * H_ * 4));
  unsigned short* h_pp  = (unsigned short*)((char*)d_ws + nb((size_t)2 * B_ * H_ * 2));  // 256KB
  unsigned*       slt   = (unsigned*)((char*)d_ws + nb((size_t)L_ * 64 * 4));
  (void)ws_size; (void)in_sizes; (void)n_in; (void)out_size;

  const int WLAYER = 4 * H_ * H_;

  k_zero<<<1, 256, 0, stream>>>(slt, L_ * 64);
  k_wt_i2h<<<(AS_ * H_ + 255) / 256, 256, 0, stream>>>(Wi2h, bi2h, Wt);
  k_f2b<<<(L_ * WLAYER + 255) / 256, 256, 0, stream>>>(Wih, Wihb, L_ * WLAYER);
  k_f2b<<<(AS_ * H_ + 255) / 256, 256, 0, stream>>>(Wh2o, Wh2ob, AS_ * H_);
  k_bias<<<(L_ * 4 * H_ + 255) / 256, 256, 0, stream>>>(bih, bhh, bsum, L_ * 4 * H_);
  k_gather<<<B_ * T_, 128, 0, stream>>>(seq, Wt, xbf);

  // out = x @ W_h2O^T + b  (faithful to reference bug: uses x, not LSTM output)
  k_gemm<0><<<dim3(B_ * T_ / 128, AS_ / 128), 256, 0, stream>>>(
      xbf, Wh2ob, bh2o, (void*)outF, B_ * T_, AS_, H_);

  float* hT_base = outF + (size_t)B_ * T_ * AS_;
  float* cT_base = hT_base + (size_t)L_ * B_ * H_;

  for (int l = 0; l < L_; ++l) {
    const unsigned short* Ain = (l == 0) ? xbf : (l == 1) ? seqA : xbf;
    unsigned short* oseq = (l == 0) ? seqA : (l == 1) ? xbf : nullptr;
    k_gemm<2><<<dim3(B_ * T_ / 128, 4 * H_ / 128), 256, 0, stream>>>(
        Ain, Wihb + (size_t)l * WLAYER, bsum + (size_t)l * 4 * H_, (void*)xgs,
        B_ * T_, 4 * H_, H_);
    k_scan<<<64, 512, 0, stream>>>(
        xgs, Whh + (size_t)l * WLAYER, h_pp, oseq,
        hT_base + (size_t)l * B_ * H_, cT_base + (size_t)l * B_ * H_,
        h0 + (size_t)l * B_ * H_, c0 + (size_t)l * B_ * H_,
        slt + (size_t)l * 64);
  }
}

// Round 11
// 4518.488 us; speedup vs baseline: 2.1368x; 2.1368x over previous
//
#include <hip/hip_runtime.h>
#include <stdint.h>
#include <stddef.h>

#define B_  64
#define T_  256
#define H_  1024
#define AS_ 128
#define L_  3

typedef __attribute__((ext_vector_type(8))) short bf16x8;
typedef __attribute__((ext_vector_type(4))) float f32x4;
typedef __attribute__((ext_vector_type(4))) unsigned u32x4;

__device__ __forceinline__ unsigned short f2bf(float f) {
  union { float f; unsigned u; } x; x.f = f;
  unsigned r = x.u + 0x7fffu + ((x.u >> 16) & 1u);   // RNE
  return (unsigned short)(r >> 16);
}
__device__ __forceinline__ float bf2f(unsigned short s) {
  union { unsigned u; float f; } x; x.u = ((unsigned)s) << 16; return x.f;
}
__device__ __forceinline__ float sigmf(float x) { return 1.0f / (1.0f + __expf(-x)); }
__device__ __forceinline__ float tanh_f(float x) {
  x = fminf(fmaxf(x, -15.0f), 15.0f);
  float e = __expf(2.0f * x);
  return (e - 1.0f) / (e + 1.0f);
}

// ---- device-coherent (MALL) accessors: relaxed agent atomics — proven R2/R5/R8/R9 ----
__device__ __forceinline__ void st_u16_cc(unsigned short* p, unsigned short v) {
  __hip_atomic_store(p, v, __ATOMIC_RELAXED, __HIP_MEMORY_SCOPE_AGENT);
}
__device__ __forceinline__ void st_u32_cc(unsigned* p, unsigned v) {
  __hip_atomic_store(p, v, __ATOMIC_RELAXED, __HIP_MEMORY_SCOPE_AGENT);
}
__device__ __forceinline__ unsigned ld_u32_cc(const unsigned* p) {
  return __hip_atomic_load(p, __ATOMIC_RELAXED, __HIP_MEMORY_SCOPE_AGENT);
}
// full-bypass 16B load, no wait (bulk) — same cache bits the compiler uses for agent atomics
__device__ __forceinline__ u32x4 ld_b128_cc_nw(const void* p) {
  u32x4 r;
  asm volatile("global_load_dwordx4 %0, %1, off sc0 sc1" : "=v"(r) : "v"(p));
  return r;
}
// batched completion wait: values usable only after this (rule #18 fence)
__device__ __forceinline__ void wait_vm0_tie8(u32x4& a, u32x4& b, u32x4& c, u32x4& d,
                                              u32x4& e, u32x4& f, u32x4& g, u32x4& h) {
  asm volatile("s_waitcnt vmcnt(0)"
               : "+v"(a), "+v"(b), "+v"(c), "+v"(d), "+v"(e), "+v"(f), "+v"(g), "+v"(h)
               :: "memory");
  __builtin_amdgcn_sched_barrier(0);
}

// ---------------- tiny utility kernels ----------------

__global__ void k_zero(unsigned* p, int n) {
  int i = blockIdx.x * 256 + threadIdx.x;
  if (i < n) st_u32_cc(p + i, 0u);
}

__global__ void k_wt_i2h(const float* __restrict__ W, const float* __restrict__ b,
                         unsigned short* __restrict__ Wt) {
  int id = blockIdx.x * 256 + threadIdx.x;
  if (id >= AS_ * H_) return;
  int a = id >> 10, h = id & 1023;
  Wt[id] = f2bf(W[h * AS_ + a] + b[h]);
}

__global__ void k_f2b(const float* __restrict__ s, unsigned short* __restrict__ d, int n) {
  int i = blockIdx.x * 256 + threadIdx.x;
  if (i < n) d[i] = f2bf(s[i]);
}

__global__ void k_bias(const float* __restrict__ bi, const float* __restrict__ bh,
                       float* __restrict__ o, int n) {
  int i = blockIdx.x * 256 + threadIdx.x;
  if (i < n) o[i] = bi[i] + bh[i];
}

__global__ __launch_bounds__(128) void k_gather(const float* __restrict__ seq,
                                                const unsigned short* __restrict__ Wt,
                                                unsigned short* __restrict__ xbf) {
  __shared__ int sidx;
  const int bt = blockIdx.x, tid = threadIdx.x;
  if (seq[(size_t)bt * AS_ + tid] > 0.5f) sidx = tid;
  __syncthreads();
  const uint4* s = (const uint4*)(Wt + (size_t)sidx * H_);
  uint4* d = (uint4*)(xbf + (size_t)bt * H_);
  d[tid] = s[tid];
}

// ---------------- MFMA GEMM ----------------
// OUT==0: float row-major [M][N].  OUT==2: bf16 scan-native (uu=32) layout:
// idx = ((t*4+gb)<<16) | (ug<<11) | (b_local<<7) | (u_local<<2) | gate

__device__ __forceinline__ void gld16(const void* g, void* l) {
  __builtin_amdgcn_global_load_lds((const __attribute__((address_space(1))) unsigned int*)g,
                                   (__attribute__((address_space(3))) unsigned int*)l,
                                   16, 0, 0);
}

template <int OUT>
__global__ __launch_bounds__(256) void k_gemm(const unsigned short* __restrict__ A,
                                              const unsigned short* __restrict__ Bm,
                                              const float* __restrict__ bias,
                                              void* __restrict__ Cout,
                                              int M, int N, int K) {
  __shared__ __align__(16) unsigned short As[128 * 32];
  __shared__ __align__(16) unsigned short Bs[128 * 32];
  const int tid = threadIdx.x, lane = tid & 63, wv = tid >> 6;
  const int m0 = blockIdx.x * 128, n0 = blockIdx.y * 128;
  const int wr = wv >> 1, wc = wv & 1;
  const int kg = lane >> 4, li = lane & 15;
  f32x4 acc[4][4] = {};

  for (int k0 = 0; k0 < K; k0 += 32) {
    for (int i = 0; i < 2; ++i) {
      int c0 = i * 256 + wv * 64;
      int cid = c0 + lane;
      int row = cid >> 2, lc = cid & 3;
      int sc = lc ^ ((row >> 1) & 3);
      gld16(A + (size_t)(m0 + row) * K + k0 + sc * 8, (char*)As + (size_t)c0 * 16);
      gld16(Bm + (size_t)(n0 + row) * K + k0 + sc * 8, (char*)Bs + (size_t)c0 * 16);
    }
    __syncthreads();
    bf16x8 af[4], bfm[4];
#pragma unroll
    for (int mi = 0; mi < 4; ++mi) {
      int row = wr * 64 + mi * 16 + li;
      int pc = kg ^ ((row >> 1) & 3);
      af[mi] = *(const bf16x8*)((const char*)As + row * 64 + pc * 16);
    }
#pragma unroll
    for (int ni = 0; ni < 4; ++ni) {
      int row = wc * 64 + ni * 16 + li;
      int pc = kg ^ ((row >> 1) & 3);
      bfm[ni] = *(const bf16x8*)((const char*)Bs + row * 64 + pc * 16);
    }
#pragma unroll
    for (int mi = 0; mi < 4; ++mi)
#pragma unroll
      for (int ni = 0; ni < 4; ++ni)
        acc[mi][ni] = __builtin_amdgcn_mfma_f32_16x16x32_bf16(af[mi], bfm[ni], acc[mi][ni], 0, 0, 0);
    __syncthreads();
  }

#pragma unroll
  for (int mi = 0; mi < 4; ++mi)
#pragma unroll
    for (int ni = 0; ni < 4; ++ni)
#pragma unroll
      for (int r = 0; r < 4; ++r) {
        int row = m0 + wr * 64 + mi * 16 + kg * 4 + r;
        int col = n0 + wc * 64 + ni * 16 + li;
        float v = acc[mi][ni][r] + bias[col];
        if (OUT == 0) {
          ((float*)Cout)[(size_t)row * N + col] = v;
        } else {
          int b = row >> 8, tt = row & 255;
          int g = col >> 10, u = col & 1023;
          int idx = ((tt * 4 + (b >> 4)) << 16) | ((u >> 5) << 11) |
                    ((b & 15) << 7) | ((u & 31) << 2) | g;
          ((unsigned short*)Cout)[idx] = f2bf(v);
        }
      }
}

// ---------------- persistent LSTM scan: R9 structure + wide bulk + coalesced publish ----------------
// 128 wgs (gb in [0,4), ug in [0,32)): batches [gb*16,+16) x units [ug*32,+32).
// Weights: 16 rows/wave in VGPR (afr, loop-invariant) + 16 rows/wave in LDS (128KB).
// Per step: poll 32 slots -> bulk read 32KB/wg as 16B sc0sc1 loads -> LDS -> MFMA
// (reg-A + LDS-A share one B-frag read) -> lane-local update -> LDS transpose ->
// coalesced u32 publishes -> drain -> slot -> out_seq (off critical path).

__global__ __launch_bounds__(256, 1) void k_scan(
    const unsigned short* __restrict__ xgs,   // scan-native (see k_gemm OUT=2)
    const float* __restrict__ Whh,            // [4H][H] f32
    unsigned short* __restrict__ h_pp,        // [2][B][H] bf16 (MALL)
    unsigned short* __restrict__ out_seq,     // [B*T][H] bf16 or null
    float* __restrict__ hT, float* __restrict__ cT,
    const float* __restrict__ h0, const float* __restrict__ c0,
    unsigned* __restrict__ slots) {           // [32] this gb-row handled via +gb*32
  __shared__ __align__(16) unsigned short Wlds[64 * 1024];   // 128 KB
  __shared__ __align__(16) unsigned short Hs[16 * 1024];     // 32 KB (exch aliases head)
  const int tid = threadIdx.x, lane = tid & 63, w = tid >> 6;
  const int gb = blockIdx.x >> 5, ug = blockIdx.x & 31;
  const int li = lane & 15, kq = lane >> 4;
  const int b  = gb * 16 + li;
  const int u0 = ug * 32 + w * 8 + kq;        // acc0's unit
  const int u1 = u0 + 4;                      // acc1's unit

  // ---- publish h0 (read parity 1 at t=0); settles during weight staging
  st_u16_cc(&h_pp[((size_t)B_ + b) * H_ + u0], f2bf(h0[(size_t)b * H_ + u0]));
  st_u16_cc(&h_pp[((size_t)B_ + b) * H_ + u1], f2bf(h0[(size_t)b * H_ + u1]));

  // ---- register A-fragments: rows r0 = w*32+li (16 rows/wave), all K
  bf16x8 afr[32];
  {
    const int r0 = w * 32 + li;               // u_local = r0>>2, gate = r0&3
    const float* wr = Whh + ((size_t)(r0 & 3) * H_ + ug * 32 + (r0 >> 2)) * H_ + kq * 8;
#pragma unroll
    for (int ks = 0; ks < 32; ++ks) {
      const float4 f0 = *(const float4*)(wr + ks * 32);
      const float4 f1 = *(const float4*)(wr + ks * 32 + 4);
      union { ushort4 a[2]; bf16x8 v; } uu_;
      uu_.a[0] = ushort4{f2bf(f0.x), f2bf(f0.y), f2bf(f0.z), f2bf(f0.w)};
      uu_.a[1] = ushort4{f2bf(f1.x), f2bf(f1.y), f2bf(f1.z), f2bf(f1.w)};
      afr[ks] = uu_.v;
    }
  }
  // ---- LDS A tile: rows r = w*32+16+it -> LDS row w*16+it (XOR swizzle by it&7)
  for (int it = 0; it < 16; ++it) {
    const int r = w * 32 + 16 + it;
    const float* wr = Whh + ((size_t)(r & 3) * H_ + ug * 32 + (r >> 2)) * H_;
#pragma unroll
    for (int j = 0; j < 4; ++j) {
      const float4 f = *(const float4*)(wr + lane * 16 + j * 4);
      ushort4 p = ushort4{f2bf(f.x), f2bf(f.y), f2bf(f.z), f2bf(f.w)};
      const int k = lane * 16 + j * 4;
      *(ushort4*)((char*)Wlds + (size_t)(w * 16 + it) * 2048 + ((2 * k) ^ ((it & 7) << 4))) = p;
    }
  }
  float cs0 = c0[(size_t)b * H_ + u0], cs1 = c0[(size_t)b * H_ + u1];
  __syncthreads();                            // drains h0 publishes (per-wave vmcnt0)
  unsigned* slmy = slots + gb * 32 + ug;
  const unsigned* sl = slots + gb * 32;
  if (tid == 0) {
    st_u32_cc(slmy, 1u);
    asm volatile("s_waitcnt vmcnt(0)" ::: "memory");
  }

  const char* hbase = (const char*)Hs + (size_t)li * 2048;
  const char* wlb   = (const char*)Wlds + (size_t)(w * 16 + li) * 2048;
  const int fxor = (li & 7) << 4;
  const int sb = tid >> 4, seg = tid & 15;
  const int sswz = (sb & 7) << 4;
  char* drow = (char*)Hs + (size_t)sb * 2048;
  unsigned short* exch = Hs;                  // [16][32] u16, 1 KB, phase-separated

  for (int t = 0; t < T_; ++t) {
    // ---- poll the 32 slots (one 128B coalesced read per pass)
    if (w == 0) {
      const unsigned tgt = (unsigned)(t + 1);
      unsigned v;
      do {
        __builtin_amdgcn_s_sleep(1);
        v = ld_u32_cc(&sl[lane & 31]);
      } while (__any((int)(v < tgt)));
    }
    __syncthreads();

    // ---- bulk read 128B/thread as 8 x 16B bypass loads (rotated), batched wait -> LDS
    {
      const char* src = (const char*)(h_pp + (size_t)((t & 1) ^ 1) * (B_ * H_) +
                                      (size_t)(gb * 16 + sb) * H_) + seg * 128;
      const int o0 = ((0 + seg) & 7) * 16, o1 = ((1 + seg) & 7) * 16;
      const int o2 = ((2 + seg) & 7) * 16, o3 = ((3 + seg) & 7) * 16;
      const int o4 = ((4 + seg) & 7) * 16, o5 = ((5 + seg) & 7) * 16;
      const int o6 = ((6 + seg) & 7) * 16, o7 = ((7 + seg) & 7) * 16;
      u32x4 t0 = ld_b128_cc_nw(src + o0), t1 = ld_b128_cc_nw(src + o1);
      u32x4 t2 = ld_b128_cc_nw(src + o2), t3 = ld_b128_cc_nw(src + o3);
      u32x4 t4 = ld_b128_cc_nw(src + o4), t5 = ld_b128_cc_nw(src + o5);
      u32x4 t6 = ld_b128_cc_nw(src + o6), t7 = ld_b128_cc_nw(src + o7);
      wait_vm0_tie8(t0, t1, t2, t3, t4, t5, t6, t7);
      *(u32x4*)(drow + ((seg * 128 + o0) ^ sswz)) = t0;
      *(u32x4*)(drow + ((seg * 128 + o1) ^ sswz)) = t1;
      *(u32x4*)(drow + ((seg * 128 + o2) ^ sswz)) = t2;
      *(u32x4*)(drow + ((seg * 128 + o3) ^ sswz)) = t3;
      *(u32x4*)(drow + ((seg * 128 + o4) ^ sswz)) = t4;
      *(u32x4*)(drow + ((seg * 128 + o5) ^ sswz)) = t5;
      *(u32x4*)(drow + ((seg * 128 + o6) ^ sswz)) = t6;
      *(u32x4*)(drow + ((seg * 128 + o7) ^ sswz)) = t7;
    }
    // ---- xv: two u64 (4 gates each for u0,u1), coalesced scan-native layout
    const size_t xb2 = ((((size_t)t * 4 + gb) << 16) | (ug << 11) | (li << 7) |
                        ((w * 8 + kq) << 2)) * 2;
    const ushort4 xa = *(const ushort4*)((const char*)xgs + xb2);
    const ushort4 xb = *(const ushort4*)((const char*)xgs + xb2 + 32);
    __syncthreads();                          // Hs staged

    // ---- MFMA: one h B-frag feeds reg-A (acc0) and LDS-A (acc1)
    f32x4 a0 = {0.f, 0.f, 0.f, 0.f}, a1 = {0.f, 0.f, 0.f, 0.f};
#pragma unroll
    for (int ks = 0; ks < 32; ++ks) {
      const bf16x8 bb = *(const bf16x8*)(hbase + ((ks * 64 + kq * 16) ^ fxor));
      a0 = __builtin_amdgcn_mfma_f32_16x16x32_bf16(afr[ks], bb, a0, 0, 0, 0);
      const bf16x8 aw = *(const bf16x8*)(wlb + ((ks * 64 + kq * 16) ^ fxor));
      a1 = __builtin_amdgcn_mfma_f32_16x16x32_bf16(aw, bb, a1, 0, 0, 0);
    }

    // ---- lane-local cell update (2 units x 4 gates)
    float h0v, h1v;
    {
      float gi = a0[0] + bf2f(xa.x), gf = a0[1] + bf2f(xa.y);
      float gg = a0[2] + bf2f(xa.z), go = a0[3] + bf2f(xa.w);
      float ci = sigmf(gf) * cs0 + sigmf(gi) * tanh_f(gg);
      cs0 = ci; h0v = sigmf(go) * tanh_f(ci);
    }
    {
      float gi = a1[0] + bf2f(xb.x), gf = a1[1] + bf2f(xb.y);
      float gg = a1[2] + bf2f(xb.z), go = a1[3] + bf2f(xb.w);
      float ci = sigmf(gf) * cs1 + sigmf(gi) * tanh_f(gg);
      cs1 = ci; h1v = sigmf(go) * tanh_f(ci);
    }
    const unsigned short hb0 = f2bf(h0v), hb1 = f2bf(h1v);

    // ---- LDS transpose for coalesced publish: exch[b_local][u_local]
    __syncthreads();                          // all Hs MFMA reads done
    exch[li * 32 + w * 8 + kq]     = hb0;
    exch[li * 32 + w * 8 + kq + 4] = hb1;
    __syncthreads();

    if (t < T_ - 1) {
      // coalesced publish: 16-thread groups write 64B runs of u32
      const int bl = tid >> 4, j = tid & 15;
      const unsigned pack = (unsigned)exch[bl * 32 + 2 * j] |
                            ((unsigned)exch[bl * 32 + 2 * j + 1] << 16);
      st_u32_cc((unsigned*)&h_pp[((size_t)(t & 1) * B_ + gb * 16 + bl) * H_ + ug * 32 + 2 * j],
                pack);
      asm volatile("s_waitcnt vmcnt(0)" ::: "memory");
      __syncthreads();                        // all publishes drained
      if (tid == 0) {
        st_u32_cc(slmy, (unsigned)(t + 2));
        asm volatile("s_waitcnt vmcnt(0)" ::: "memory");
      }
    } else {
      hT[(size_t)b * H_ + u0] = h0v; hT[(size_t)b * H_ + u1] = h1v;
      cT[(size_t)b * H_ + u0] = cs0; cT[(size_t)b * H_ + u1] = cs1;
    }

    // ---- out_seq: off critical path, coalesced 16B stores from exch
    if (out_seq && tid < 64) {
      const int bo = tid >> 2, q = tid & 3;
      *(u32x4*)&out_seq[((size_t)(gb * 16 + bo) * T_ + t) * H_ + ug * 32 + 8 * q] =
          *(const u32x4*)&exch[bo * 32 + 8 * q];
    }
  }
}

// ---------------- launcher ----------------

extern "C" void kernel_launch(void* const* d_in, const int* in_sizes, int n_in,
                              void* d_out, int out_size, void* d_ws, size_t ws_size,
                              hipStream_t stream) {
  const float* seq  = (const float*)d_in[0];
  const float* Wi2h = (const float*)d_in[1];
  const float* bi2h = (const float*)d_in[2];
  const float* Wih  = (const float*)d_in[3];
  const float* Whh  = (const float*)d_in[4];
  const float* bih  = (const float*)d_in[5];
  const float* bhh  = (const float*)d_in[6];
  const float* Wh2o = (const float*)d_in[7];
  const float* bh2o = (const float*)d_in[8];
  const float* h0   = (const float*)d_in[9];
  const float* c0   = (const float*)d_in[10];
  float* outF = (float*)d_out;

  size_t off = 0;
  auto nb = [&](size_t bytes) { size_t r = off; off += (bytes + 255) & ~(size_t)255; return r; };
  unsigned short* xbf   = (unsigned short*)((char*)d_ws + nb((size_t)B_ * T_ * H_ * 2));
  unsigned short* seqA  = (unsigned short*)((char*)d_ws + nb((size_t)B_ * T_ * H_ * 2));
  unsigned short* xgs   = (unsigned short*)((char*)d_ws + nb((size_t)B_ * T_ * 4 * H_ * 2));
  unsigned short* Wihb  = (unsigned short*)((char*)d_ws + nb((size_t)L_ * 4 * H_ * H_ * 2));
  unsigned short* Wh2ob = (unsigned short*)((char*)d_ws + nb((size_t)AS_ * H_ * 2));
  unsigned short* Wt    = (unsigned short*)((char*)d_ws + nb((size_t)AS_ * H_ * 2));
  float*          bsum  = (float*)((char*)d_ws + nb((size_t)L_ * 4 * H_ * 4));
  unsigned short* h_pp  = (unsigned short*)((char*)d_ws + nb((size_t)2 * B_ * H_ * 2));  // 256KB
  unsigned*       slt   = (unsigned*)((char*)d_ws + nb((size_t)L_ * 128 * 4));
  (void)ws_size; (void)in_sizes; (void)n_in; (void)out_size;

  const int WLAYER = 4 * H_ * H_;

  k_zero<<<2, 256, 0, stream>>>(slt, L_ * 128);
  k_wt_i2h<<<(AS_ * H_ + 255) / 256, 256, 0, stream>>>(Wi2h, bi2h, Wt);
  k_f2b<<<(L_ * WLAYER + 255) / 256, 256, 0, stream>>>(Wih, Wihb, L_ * WLAYER);
  k_f2b<<<(AS_ * H_ + 255) / 256, 256, 0, stream>>>(Wh2o, Wh2ob, AS_ * H_);
  k_bias<<<(L_ * 4 * H_ + 255) / 256, 256, 0, stream>>>(bih, bhh, bsum, L_ * 4 * H_);
  k_gather<<<B_ * T_, 128, 0, stream>>>(seq, Wt, xbf);

  // out = x @ W_h2O^T + b  (faithful to reference bug: uses x, not LSTM output)
  k_gemm<0><<<dim3(B_ * T_ / 128, AS_ / 128), 256, 0, stream>>>(
      xbf, Wh2ob, bh2o, (void*)outF, B_ * T_, AS_, H_);

  float* hT_base = outF + (size_t)B_ * T_ * AS_;
  float* cT_base = hT_base + (size_t)L_ * B_ * H_;

  for (int l = 0; l < L_; ++l) {
    const unsigned short* Ain = (l == 0) ? xbf : (l == 1) ? seqA : xbf;
    unsigned short* oseq = (l == 0) ? seqA : (l == 1) ? xbf : nullptr;
    k_gemm<2><<<dim3(B_ * T_ / 128, 4 * H_ / 128), 256, 0, stream>>>(
        Ain, Wihb + (size_t)l * WLAYER, bsum + (size_t)l * 4 * H_, (void*)xgs,
        B_ * T_, 4 * H_, H_);
    k_scan<<<128, 256, 0, stream>>>(
        xgs, Whh + (size_t)l * WLAYER, h_pp, oseq,
        hT_base + (size_t)l * B_ * H_, cT_base + (size_t)l * B_ * H_,
        h0 + (size_t)l * B_ * H_, c0 + (size_t)l * B_ * H_,
        slt + (size_t)l * 128);
  }
}

// Round 12
// 4452.821 us; speedup vs baseline: 2.1683x; 1.0147x over previous
//
#include <hip/hip_runtime.h>
#include <stdint.h>
#include <stddef.h>

#define B_  64
#define T_  256
#define H_  1024
#define AS_ 128
#define L_  3

typedef __attribute__((ext_vector_type(8))) short bf16x8;
typedef __attribute__((ext_vector_type(4))) float f32x4;
typedef __attribute__((ext_vector_type(4))) unsigned u32x4;

__device__ __forceinline__ unsigned short f2bf(float f) {
  union { float f; unsigned u; } x; x.f = f;
  unsigned r = x.u + 0x7fffu + ((x.u >> 16) & 1u);   // RNE
  return (unsigned short)(r >> 16);
}
__device__ __forceinline__ float bf2f(unsigned short s) {
  union { unsigned u; float f; } x; x.u = ((unsigned)s) << 16; return x.f;
}
__device__ __forceinline__ float sigmf(float x) { return 1.0f / (1.0f + __expf(-x)); }
__device__ __forceinline__ float tanh_f(float x) {
  x = fminf(fmaxf(x, -15.0f), 15.0f);
  float e = __expf(2.0f * x);
  return (e - 1.0f) / (e + 1.0f);
}

// ---- device-coherent (MALL) accessors: relaxed agent atomics — proven R2..R11 ----
__device__ __forceinline__ void st_u16_cc(unsigned short* p, unsigned short v) {
  __hip_atomic_store(p, v, __ATOMIC_RELAXED, __HIP_MEMORY_SCOPE_AGENT);
}
__device__ __forceinline__ void st_u32_cc(unsigned* p, unsigned v) {
  __hip_atomic_store(p, v, __ATOMIC_RELAXED, __HIP_MEMORY_SCOPE_AGENT);
}
__device__ __forceinline__ unsigned ld_u32_cc(const unsigned* p) {
  return __hip_atomic_load(p, __ATOMIC_RELAXED, __HIP_MEMORY_SCOPE_AGENT);
}
// full-bypass 16B load, no wait (bulk) — proven R11
__device__ __forceinline__ u32x4 ld_b128_cc_nw(const void* p) {
  u32x4 r;
  asm volatile("global_load_dwordx4 %0, %1, off sc0 sc1" : "=v"(r) : "v"(p));
  return r;
}
// batched completion wait: values usable only after this (rule #18 fence)
__device__ __forceinline__ void wait_vm0_tie8(u32x4& a, u32x4& b, u32x4& c, u32x4& d,
                                              u32x4& e, u32x4& f, u32x4& g, u32x4& h) {
  asm volatile("s_waitcnt vmcnt(0)"
               : "+v"(a), "+v"(b), "+v"(c), "+v"(d), "+v"(e), "+v"(f), "+v"(g), "+v"(h)
               :: "memory");
  __builtin_amdgcn_sched_barrier(0);
}

// ---------------- tiny utility kernels ----------------

__global__ void k_zero(unsigned* p, int n) {
  int i = blockIdx.x * 256 + threadIdx.x;
  if (i < n) st_u32_cc(p + i, 0u);
}

__global__ void k_wt_i2h(const float* __restrict__ W, const float* __restrict__ b,
                         unsigned short* __restrict__ Wt) {
  int id = blockIdx.x * 256 + threadIdx.x;
  if (id >= AS_ * H_) return;
  int a = id >> 10, h = id & 1023;
  Wt[id] = f2bf(W[h * AS_ + a] + b[h]);
}

__global__ void k_f2b(const float* __restrict__ s, unsigned short* __restrict__ d, int n) {
  int i = blockIdx.x * 256 + threadIdx.x;
  if (i < n) d[i] = f2bf(s[i]);
}

__global__ void k_bias(const float* __restrict__ bi, const float* __restrict__ bh,
                       float* __restrict__ o, int n) {
  int i = blockIdx.x * 256 + threadIdx.x;
  if (i < n) o[i] = bi[i] + bh[i];
}

__global__ __launch_bounds__(128) void k_gather(const float* __restrict__ seq,
                                                const unsigned short* __restrict__ Wt,
                                                unsigned short* __restrict__ xbf) {
  __shared__ int sidx;
  const int bt = blockIdx.x, tid = threadIdx.x;
  if (seq[(size_t)bt * AS_ + tid] > 0.5f) sidx = tid;
  __syncthreads();
  const uint4* s = (const uint4*)(Wt + (size_t)sidx * H_);
  uint4* d = (uint4*)(xbf + (size_t)bt * H_);
  d[tid] = s[tid];
}

// ---------------- MFMA GEMM ----------------
// OUT==0: float row-major [M][N].  OUT==2: bf16 scan-native (uu=32) layout:
// idx = ((t*4+gb)<<16) | (ug<<11) | (b_local<<7) | (u_local<<2) | gate

__device__ __forceinline__ void gld16(const void* g, void* l) {
  __builtin_amdgcn_global_load_lds((const __attribute__((address_space(1))) unsigned int*)g,
                                   (__attribute__((address_space(3))) unsigned int*)l,
                                   16, 0, 0);
}

template <int OUT>
__global__ __launch_bounds__(256) void k_gemm(const unsigned short* __restrict__ A,
                                              const unsigned short* __restrict__ Bm,
                                              const float* __restrict__ bias,
                                              void* __restrict__ Cout,
                                              int M, int N, int K) {
  __shared__ __align__(16) unsigned short As[128 * 32];
  __shared__ __align__(16) unsigned short Bs[128 * 32];
  const int tid = threadIdx.x, lane = tid & 63, wv = tid >> 6;
  const int m0 = blockIdx.x * 128, n0 = blockIdx.y * 128;
  const int wr = wv >> 1, wc = wv & 1;
  const int kg = lane >> 4, li = lane & 15;
  f32x4 acc[4][4] = {};

  for (int k0 = 0; k0 < K; k0 += 32) {
    for (int i = 0; i < 2; ++i) {
      int c0 = i * 256 + wv * 64;
      int cid = c0 + lane;
      int row = cid >> 2, lc = cid & 3;
      int sc = lc ^ ((row >> 1) & 3);
      gld16(A + (size_t)(m0 + row) * K + k0 + sc * 8, (char*)As + (size_t)c0 * 16);
      gld16(Bm + (size_t)(n0 + row) * K + k0 + sc * 8, (char*)Bs + (size_t)c0 * 16);
    }
    __syncthreads();
    bf16x8 af[4], bfm[4];
#pragma unroll
    for (int mi = 0; mi < 4; ++mi) {
      int row = wr * 64 + mi * 16 + li;
      int pc = kg ^ ((row >> 1) & 3);
      af[mi] = *(const bf16x8*)((const char*)As + row * 64 + pc * 16);
    }
#pragma unroll
    for (int ni = 0; ni < 4; ++ni) {
      int row = wc * 64 + ni * 16 + li;
      int pc = kg ^ ((row >> 1) & 3);
      bfm[ni] = *(const bf16x8*)((const char*)Bs + row * 64 + pc * 16);
    }
#pragma unroll
    for (int mi = 0; mi < 4; ++mi)
#pragma unroll
      for (int ni = 0; ni < 4; ++ni)
        acc[mi][ni] = __builtin_amdgcn_mfma_f32_16x16x32_bf16(af[mi], bfm[ni], acc[mi][ni], 0, 0, 0);
    __syncthreads();
  }

#pragma unroll
  for (int mi = 0; mi < 4; ++mi)
#pragma unroll
    for (int ni = 0; ni < 4; ++ni)
#pragma unroll
      for (int r = 0; r < 4; ++r) {
        int row = m0 + wr * 64 + mi * 16 + kg * 4 + r;
        int col = n0 + wc * 64 + ni * 16 + li;
        float v = acc[mi][ni][r] + bias[col];
        if (OUT == 0) {
          ((float*)Cout)[(size_t)row * N + col] = v;
        } else {
          int b = row >> 8, tt = row & 255;
          int g = col >> 10, u = col & 1023;
          int idx = ((tt * 4 + (b >> 4)) << 16) | ((u >> 5) << 11) |
                    ((b & 15) << 7) | ((u & 31) << 2) | g;
          ((unsigned short*)Cout)[idx] = f2bf(v);
        }
      }
}

// ---------------- persistent LSTM scan: R11 + per-consumer slot replicas ----------------
// 128 wgs (gb in [0,4), ug in [0,32)): batches [gb*16,+16) x units [ug*32,+32).
// Slot replicas: slots[gb][consumer][producer] u32 (32 lines of 128B per gb).
// Producer publishes h (coalesced u32 bypass stores, per-thread drain, barrier),
// then wave-3 lanes 0..31 write slot value into ALL 32 consumer lines in parallel
// (one store each + drain) — each consumer polls its PRIVATE line (1 wg/line,
// kills the 2048-lane hot-line serialization). Poller = wave 0 (role split).

__global__ __launch_bounds__(256, 1) void k_scan(
    const unsigned short* __restrict__ xgs,   // scan-native (see k_gemm OUT=2)
    const float* __restrict__ Whh,            // [4H][H] f32
    unsigned short* __restrict__ h_pp,        // [2][B][H] bf16 (MALL)
    unsigned short* __restrict__ out_seq,     // [B*T][H] bf16 or null
    float* __restrict__ hT, float* __restrict__ cT,
    const float* __restrict__ h0, const float* __restrict__ c0,
    unsigned* __restrict__ slots) {           // [4][32][32] this layer
  __shared__ __align__(16) unsigned short Wlds[64 * 1024];   // 128 KB
  __shared__ __align__(16) unsigned short Hs[16 * 1024];     // 32 KB (exch aliases head)
  const int tid = threadIdx.x, lane = tid & 63, w = tid >> 6;
  const int gb = blockIdx.x >> 5, ug = blockIdx.x & 31;
  const int li = lane & 15, kq = lane >> 4;
  const int b  = gb * 16 + li;
  const int u0 = ug * 32 + w * 8 + kq;        // acc0's unit
  const int u1 = u0 + 4;                      // acc1's unit

  // ---- publish h0 (read parity 1 at t=0); settles during weight staging
  st_u16_cc(&h_pp[((size_t)B_ + b) * H_ + u0], f2bf(h0[(size_t)b * H_ + u0]));
  st_u16_cc(&h_pp[((size_t)B_ + b) * H_ + u1], f2bf(h0[(size_t)b * H_ + u1]));

  // ---- register A-fragments: rows r0 = w*32+li (16 rows/wave), all K
  bf16x8 afr[32];
  {
    const int r0 = w * 32 + li;               // u_local = r0>>2, gate = r0&3
    const float* wr = Whh + ((size_t)(r0 & 3) * H_ + ug * 32 + (r0 >> 2)) * H_ + kq * 8;
#pragma unroll
    for (int ks = 0; ks < 32; ++ks) {
      const float4 f0 = *(const float4*)(wr + ks * 32);
      const float4 f1 = *(const float4*)(wr + ks * 32 + 4);
      union { ushort4 a[2]; bf16x8 v; } uu_;
      uu_.a[0] = ushort4{f2bf(f0.x), f2bf(f0.y), f2bf(f0.z), f2bf(f0.w)};
      uu_.a[1] = ushort4{f2bf(f1.x), f2bf(f1.y), f2bf(f1.z), f2bf(f1.w)};
      afr[ks] = uu_.v;
    }
  }
  // ---- LDS A tile: rows r = w*32+16+it -> LDS row w*16+it (XOR swizzle by it&7)
  for (int it = 0; it < 16; ++it) {
    const int r = w * 32 + 16 + it;
    const float* wr = Whh + ((size_t)(r & 3) * H_ + ug * 32 + (r >> 2)) * H_;
#pragma unroll
    for (int j = 0; j < 4; ++j) {
      const float4 f = *(const float4*)(wr + lane * 16 + j * 4);
      ushort4 p = ushort4{f2bf(f.x), f2bf(f.y), f2bf(f.z), f2bf(f.w)};
      const int k = lane * 16 + j * 4;
      *(ushort4*)((char*)Wlds + (size_t)(w * 16 + it) * 2048 + ((2 * k) ^ ((it & 7) << 4))) = p;
    }
  }
  float cs0 = c0[(size_t)b * H_ + u0], cs1 = c0[(size_t)b * H_ + u1];
  __syncthreads();                            // drains h0 publishes (per-wave vmcnt0)
  // initial slot=1 to all 32 consumer replicas (wave 3, 32 parallel stores)
  if (w == 3 && lane < 32) {
    st_u32_cc(&slots[gb * 1024 + lane * 32 + ug], 1u);
    asm volatile("s_waitcnt vmcnt(0)" ::: "memory");
  }

  const char* hbase = (const char*)Hs + (size_t)li * 2048;
  const char* wlb   = (const char*)Wlds + (size_t)(w * 16 + li) * 2048;
  const int fxor = (li & 7) << 4;
  const int sb = tid >> 4, seg = tid & 15;
  const int sswz = (sb & 7) << 4;
  char* drow = (char*)Hs + (size_t)sb * 2048;
  unsigned short* exch = Hs;                  // [16][32] u16, 1 KB, phase-separated
  const unsigned* myline = slots + gb * 1024 + ug * 32;   // private poll line

  for (int t = 0; t < T_; ++t) {
    // ---- xv first (HBM latency hides under the poll)
    const size_t xb2 = ((((size_t)t * 4 + gb) << 16) | (ug << 11) | (li << 7) |
                        ((w * 8 + kq) << 2)) * 2;
    const ushort4 xa = *(const ushort4*)((const char*)xgs + xb2);
    const ushort4 xb = *(const ushort4*)((const char*)xgs + xb2 + 32);

    // ---- poll private slot line (wave 0; 64 lanes read one 128B line)
    if (w == 0) {
      const unsigned tgt = (unsigned)(t + 1);
      unsigned v;
      do {
        __builtin_amdgcn_s_sleep(1);
        v = ld_u32_cc(&myline[lane & 31]);
      } while (__any((int)(v < tgt)));
    }
    __syncthreads();

    // ---- bulk read 128B/thread as 8 x 16B bypass loads (rotated), batched wait -> LDS
    {
      const char* src = (const char*)(h_pp + (size_t)((t & 1) ^ 1) * (B_ * H_) +
                                      (size_t)(gb * 16 + sb) * H_) + seg * 128;
      const int o0 = ((0 + seg) & 7) * 16, o1 = ((1 + seg) & 7) * 16;
      const int o2 = ((2 + seg) & 7) * 16, o3 = ((3 + seg) & 7) * 16;
      const int o4 = ((4 + seg) & 7) * 16, o5 = ((5 + seg) & 7) * 16;
      const int o6 = ((6 + seg) & 7) * 16, o7 = ((7 + seg) & 7) * 16;
      u32x4 t0 = ld_b128_cc_nw(src + o0), t1 = ld_b128_cc_nw(src + o1);
      u32x4 t2 = ld_b128_cc_nw(src + o2), t3 = ld_b128_cc_nw(src + o3);
      u32x4 t4 = ld_b128_cc_nw(src + o4), t5 = ld_b128_cc_nw(src + o5);
      u32x4 t6 = ld_b128_cc_nw(src + o6), t7 = ld_b128_cc_nw(src + o7);
      wait_vm0_tie8(t0, t1, t2, t3, t4, t5, t6, t7);
      *(u32x4*)(drow + ((seg * 128 + o0) ^ sswz)) = t0;
      *(u32x4*)(drow + ((seg * 128 + o1) ^ sswz)) = t1;
      *(u32x4*)(drow + ((seg * 128 + o2) ^ sswz)) = t2;
      *(u32x4*)(drow + ((seg * 128 + o3) ^ sswz)) = t3;
      *(u32x4*)(drow + ((seg * 128 + o4) ^ sswz)) = t4;
      *(u32x4*)(drow + ((seg * 128 + o5) ^ sswz)) = t5;
      *(u32x4*)(drow + ((seg * 128 + o6) ^ sswz)) = t6;
      *(u32x4*)(drow + ((seg * 128 + o7) ^ sswz)) = t7;
    }
    __syncthreads();                          // Hs staged

    // ---- MFMA: one h B-frag feeds reg-A (acc0) and LDS-A (acc1)
    f32x4 a0 = {0.f, 0.f, 0.f, 0.f}, a1 = {0.f, 0.f, 0.f, 0.f};
#pragma unroll
    for (int ks = 0; ks < 32; ++ks) {
      const bf16x8 bb = *(const bf16x8*)(hbase + ((ks * 64 + kq * 16) ^ fxor));
      a0 = __builtin_amdgcn_mfma_f32_16x16x32_bf16(afr[ks], bb, a0, 0, 0, 0);
      const bf16x8 aw = *(const bf16x8*)(wlb + ((ks * 64 + kq * 16) ^ fxor));
      a1 = __builtin_amdgcn_mfma_f32_16x16x32_bf16(aw, bb, a1, 0, 0, 0);
    }

    // ---- lane-local cell update (2 units x 4 gates)
    float h0v, h1v;
    {
      float gi = a0[0] + bf2f(xa.x), gf = a0[1] + bf2f(xa.y);
      float gg = a0[2] + bf2f(xa.z), go = a0[3] + bf2f(xa.w);
      float ci = sigmf(gf) * cs0 + sigmf(gi) * tanh_f(gg);
      cs0 = ci; h0v = sigmf(go) * tanh_f(ci);
    }
    {
      float gi = a1[0] + bf2f(xb.x), gf = a1[1] + bf2f(xb.y);
      float gg = a1[2] + bf2f(xb.z), go = a1[3] + bf2f(xb.w);
      float ci = sigmf(gf) * cs1 + sigmf(gi) * tanh_f(gg);
      cs1 = ci; h1v = sigmf(go) * tanh_f(ci);
    }
    const unsigned short hb0 = f2bf(h0v), hb1 = f2bf(h1v);

    // ---- LDS transpose for coalesced publish: exch[b_local][u_local]
    __syncthreads();                          // all Hs MFMA reads done
    exch[li * 32 + w * 8 + kq]     = hb0;
    exch[li * 32 + w * 8 + kq + 4] = hb1;
    __syncthreads();

    if (t < T_ - 1) {
      // coalesced publish: 16-thread groups write 64B runs of u32
      const int bl = tid >> 4, j = tid & 15;
      const unsigned pack = (unsigned)exch[bl * 32 + 2 * j] |
                            ((unsigned)exch[bl * 32 + 2 * j + 1] << 16);
      st_u32_cc((unsigned*)&h_pp[((size_t)(t & 1) * B_ + gb * 16 + bl) * H_ + ug * 32 + 2 * j],
                pack);
      asm volatile("s_waitcnt vmcnt(0)" ::: "memory");
      __syncthreads();                        // all publishes ACKed
      // slot = t+2 to all 32 consumer replicas (wave 3, parallel; drain overlaps w0's next poll)
      if (w == 3 && lane < 32) {
        st_u32_cc(&slots[gb * 1024 + lane * 32 + ug], (unsigned)(t + 2));
        asm volatile("s_waitcnt vmcnt(0)" ::: "memory");
      }
    } else {
      hT[(size_t)b * H_ + u0] = h0v; hT[(size_t)b * H_ + u1] = h1v;
      cT[(size_t)b * H_ + u0] = cs0; cT[(size_t)b * H_ + u1] = cs1;
    }

    // ---- out_seq: off critical path, coalesced 16B stores from exch
    if (out_seq && tid < 64) {
      const int bo = tid >> 2, q = tid & 3;
      *(u32x4*)&out_seq[((size_t)(gb * 16 + bo) * T_ + t) * H_ + ug * 32 + 8 * q] =
          *(const u32x4*)&exch[bo * 32 + 8 * q];
    }
  }
}

// ---------------- launcher ----------------

extern "C" void kernel_launch(void* const* d_in, const int* in_sizes, int n_in,
                              void* d_out, int out_size, void* d_ws, size_t ws_size,
                              hipStream_t stream) {
  const float* seq  = (const float*)d_in[0];
  const float* Wi2h = (const float*)d_in[1];
  const float* bi2h = (const float*)d_in[2];
  const float* Wih  = (const float*)d_in[3];
  const float* Whh  = (const float*)d_in[4];
  const float* bih  = (const float*)d_in[5];
  const float* bhh  = (const float*)d_in[6];
  const float* Wh2o = (const float*)d_in[7];
  const float* bh2o = (const float*)d_in[8];
  const float* h0   = (const float*)d_in[9];
  const float* c0   = (const float*)d_in[10];
  float* outF = (float*)d_out;

  size_t off = 0;
  auto nb = [&](size_t bytes) { size_t r = off; off += (bytes + 255) & ~(size_t)255; return r; };
  unsigned short* xbf   = (unsigned short*)((char*)d_ws + nb((size_t)B_ * T_ * H_ * 2));
  unsigned short* seqA  = (unsigned short*)((char*)d_ws + nb((size_t)B_ * T_ * H_ * 2));
  unsigned short* xgs   = (unsigned short*)((char*)d_ws + nb((size_t)B_ * T_ * 4 * H_ * 2));
  unsigned short* Wihb  = (unsigned short*)((char*)d_ws + nb((size_t)L_ * 4 * H_ * H_ * 2));
  unsigned short* Wh2ob = (unsigned short*)((char*)d_ws + nb((size_t)AS_ * H_ * 2));
  unsigned short* Wt    = (unsigned short*)((char*)d_ws + nb((size_t)AS_ * H_ * 2));
  float*          bsum  = (float*)((char*)d_ws + nb((size_t)L_ * 4 * H_ * 4));
  unsigned short* h_pp  = (unsigned short*)((char*)d_ws + nb((size_t)2 * B_ * H_ * 2));  // 256KB
  unsigned*       slt   = (unsigned*)((char*)d_ws + nb((size_t)L_ * 4 * 32 * 32 * 4));   // 48KB
  (void)ws_size; (void)in_sizes; (void)n_in; (void)out_size;

  const int WLAYER = 4 * H_ * H_;

  k_zero<<<(L_ * 4096 + 255) / 256, 256, 0, stream>>>(slt, L_ * 4096);
  k_wt_i2h<<<(AS_ * H_ + 255) / 256, 256, 0, stream>>>(Wi2h, bi2h, Wt);
  k_f2b<<<(L_ * WLAYER + 255) / 256, 256, 0, stream>>>(Wih, Wihb, L_ * WLAYER);
  k_f2b<<<(AS_ * H_ + 255) / 256, 256, 0, stream>>>(Wh2o, Wh2ob, AS_ * H_);
  k_bias<<<(L_ * 4 * H_ + 255) / 256, 256, 0, stream>>>(bih, bhh, bsum, L_ * 4 * H_);
  k_gather<<<B_ * T_, 128, 0, stream>>>(seq, Wt, xbf);

  // out = x @ W_h2O^T + b  (faithful to reference bug: uses x, not LSTM output)
  k_gemm<0><<<dim3(B_ * T_ / 128, AS_ / 128), 256, 0, stream>>>(
      xbf, Wh2ob, bh2o, (void*)outF, B_ * T_, AS_, H_);

  float* hT_base = outF + (size_t)B_ * T_ * AS_;
  float* cT_base = hT_base + (size_t)L_ * B_ * H_;

  for (int l = 0; l < L_; ++l) {
    const unsigned short* Ain = (l == 0) ? xbf : (l == 1) ? seqA : xbf;
    unsigned short* oseq = (l == 0) ? seqA : (l == 1) ? xbf : nullptr;
    k_gemm<2><<<dim3(B_ * T_ / 128, 4 * H_ / 128), 256, 0, stream>>>(
        Ain, Wihb + (size_t)l * WLAYER, bsum + (size_t)l * 4 * H_, (void*)xgs,
        B_ * T_, 4 * H_, H_);
    k_scan<<<128, 256, 0, stream>>>(
        xgs, Whh + (size_t)l * WLAYER, h_pp, oseq,
        hT_base + (size_t)l * B_ * H_, cT_base + (size_t)l * B_ * H_,
        h0 + (size_t)l * B_ * H_, c0 + (size_t)l * B_ * H_,
        slt + (size_t)l * 4096);
  }
}

// Round 13
// 3696.265 us; speedup vs baseline: 2.6121x; 1.2047x over previous
//
#include <hip/hip_runtime.h>
#include <stdint.h>
#include <stddef.h>

#define B_  64
#define T_  256
#define H_  1024
#define AS_ 128
#define L_  3

typedef __attribute__((ext_vector_type(8))) short bf16x8;
typedef __attribute__((ext_vector_type(4))) float f32x4;
typedef __attribute__((ext_vector_type(4))) unsigned u32x4;

__device__ __forceinline__ unsigned short f2bf(float f) {
  union { float f; unsigned u; } x; x.f = f;
  unsigned r = x.u + 0x7fffu + ((x.u >> 16) & 1u);   // RNE
  return (unsigned short)(r >> 16);
}
__device__ __forceinline__ float bf2f(unsigned short s) {
  union { unsigned u; float f; } x; x.u = ((unsigned)s) << 16; return x.f;
}
__device__ __forceinline__ float sigmf(float x) { return 1.0f / (1.0f + __expf(-x)); }
__device__ __forceinline__ float tanh_f(float x) {
  x = fminf(fmaxf(x, -15.0f), 15.0f);
  float e = __expf(2.0f * x);
  return (e - 1.0f) / (e + 1.0f);
}

// ---- device-coherent (MALL) accessors: relaxed agent atomics — proven R2..R12 ----
__device__ __forceinline__ void st_u16_cc(unsigned short* p, unsigned short v) {
  __hip_atomic_store(p, v, __ATOMIC_RELAXED, __HIP_MEMORY_SCOPE_AGENT);
}
__device__ __forceinline__ void st_u32_cc(unsigned* p, unsigned v) {
  __hip_atomic_store(p, v, __ATOMIC_RELAXED, __HIP_MEMORY_SCOPE_AGENT);
}
__device__ __forceinline__ unsigned ld_u32_cc(const unsigned* p) {
  return __hip_atomic_load(p, __ATOMIC_RELAXED, __HIP_MEMORY_SCOPE_AGENT);
}
// full-bypass 16B load, no wait (bulk) — proven R11/R12
__device__ __forceinline__ u32x4 ld_b128_cc_nw(const void* p) {
  u32x4 r;
  asm volatile("global_load_dwordx4 %0, %1, off sc0 sc1" : "=v"(r) : "v"(p));
  return r;
}
// counted waits with tied operands (rule #18: values usable only after these)
__device__ __forceinline__ void wait_vm4_tie4(u32x4& a, u32x4& b, u32x4& c, u32x4& d) {
  asm volatile("s_waitcnt vmcnt(4)"
               : "+v"(a), "+v"(b), "+v"(c), "+v"(d) :: "memory");
  __builtin_amdgcn_sched_barrier(0);
}
__device__ __forceinline__ void wait_vm0_tie4(u32x4& a, u32x4& b, u32x4& c, u32x4& d) {
  asm volatile("s_waitcnt vmcnt(0)"
               : "+v"(a), "+v"(b), "+v"(c), "+v"(d) :: "memory");
  __builtin_amdgcn_sched_barrier(0);
}
// LDS-only barrier: waits ds ops, NOT outstanding global loads (keeps B-half in flight)
__device__ __forceinline__ void lds_barrier() {
  __builtin_amdgcn_sched_barrier(0);
  asm volatile("s_waitcnt lgkmcnt(0)" ::: "memory");
  __builtin_amdgcn_sched_barrier(0);
  __builtin_amdgcn_s_barrier();
  __builtin_amdgcn_sched_barrier(0);
}

// ---------------- tiny utility kernels ----------------

__global__ void k_zero(unsigned* p, int n) {
  int i = blockIdx.x * 256 + threadIdx.x;
  if (i < n) st_u32_cc(p + i, 0u);
}

__global__ void k_wt_i2h(const float* __restrict__ W, const float* __restrict__ b,
                         unsigned short* __restrict__ Wt) {
  int id = blockIdx.x * 256 + threadIdx.x;
  if (id >= AS_ * H_) return;
  int a = id >> 10, h = id & 1023;
  Wt[id] = f2bf(W[h * AS_ + a] + b[h]);
}

__global__ void k_f2b(const float* __restrict__ s, unsigned short* __restrict__ d, int n) {
  int i = blockIdx.x * 256 + threadIdx.x;
  if (i < n) d[i] = f2bf(s[i]);
}

__global__ void k_bias(const float* __restrict__ bi, const float* __restrict__ bh,
                       float* __restrict__ o, int n) {
  int i = blockIdx.x * 256 + threadIdx.x;
  if (i < n) o[i] = bi[i] + bh[i];
}

__global__ __launch_bounds__(128) void k_gather(const float* __restrict__ seq,
                                                const unsigned short* __restrict__ Wt,
                                                unsigned short* __restrict__ xbf) {
  __shared__ int sidx;
  const int bt = blockIdx.x, tid = threadIdx.x;
  if (seq[(size_t)bt * AS_ + tid] > 0.5f) sidx = tid;
  __syncthreads();
  const uint4* s = (const uint4*)(Wt + (size_t)sidx * H_);
  uint4* d = (uint4*)(xbf + (size_t)bt * H_);
  d[tid] = s[tid];
}

// ---------------- MFMA GEMM ----------------
// OUT==0: float row-major [M][N].  OUT==2: bf16 scan-native (uu=32) layout:
// idx = ((t*4+gb)<<16) | (ug<<11) | (b_local<<7) | (u_local<<2) | gate

__device__ __forceinline__ void gld16(const void* g, void* l) {
  __builtin_amdgcn_global_load_lds((const __attribute__((address_space(1))) unsigned int*)g,
                                   (__attribute__((address_space(3))) unsigned int*)l,
                                   16, 0, 0);
}

template <int OUT>
__global__ __launch_bounds__(256) void k_gemm(const unsigned short* __restrict__ A,
                                              const unsigned short* __restrict__ Bm,
                                              const float* __restrict__ bias,
                                              void* __restrict__ Cout,
                                              int M, int N, int K) {
  __shared__ __align__(16) unsigned short As[128 * 32];
  __shared__ __align__(16) unsigned short Bs[128 * 32];
  const int tid = threadIdx.x, lane = tid & 63, wv = tid >> 6;
  const int m0 = blockIdx.x * 128, n0 = blockIdx.y * 128;
  const int wr = wv >> 1, wc = wv & 1;
  const int kg = lane >> 4, li = lane & 15;
  f32x4 acc[4][4] = {};

  for (int k0 = 0; k0 < K; k0 += 32) {
    for (int i = 0; i < 2; ++i) {
      int c0 = i * 256 + wv * 64;
      int cid = c0 + lane;
      int row = cid >> 2, lc = cid & 3;
      int sc = lc ^ ((row >> 1) & 3);
      gld16(A + (size_t)(m0 + row) * K + k0 + sc * 8, (char*)As + (size_t)c0 * 16);
      gld16(Bm + (size_t)(n0 + row) * K + k0 + sc * 8, (char*)Bs + (size_t)c0 * 16);
    }
    __syncthreads();
    bf16x8 af[4], bfm[4];
#pragma unroll
    for (int mi = 0; mi < 4; ++mi) {
      int row = wr * 64 + mi * 16 + li;
      int pc = kg ^ ((row >> 1) & 3);
      af[mi] = *(const bf16x8*)((const char*)As + row * 64 + pc * 16);
    }
#pragma unroll
    for (int ni = 0; ni < 4; ++ni) {
      int row = wc * 64 + ni * 16 + li;
      int pc = kg ^ ((row >> 1) & 3);
      bfm[ni] = *(const bf16x8*)((const char*)Bs + row * 64 + pc * 16);
    }
#pragma unroll
    for (int mi = 0; mi < 4; ++mi)
#pragma unroll
      for (int ni = 0; ni < 4; ++ni)
        acc[mi][ni] = __builtin_amdgcn_mfma_f32_16x16x32_bf16(af[mi], bfm[ni], acc[mi][ni], 0, 0, 0);
    __syncthreads();
  }

#pragma unroll
  for (int mi = 0; mi < 4; ++mi)
#pragma unroll
    for (int ni = 0; ni < 4; ++ni)
#pragma unroll
      for (int r = 0; r < 4; ++r) {
        int row = m0 + wr * 64 + mi * 16 + kg * 4 + r;
        int col = n0 + wc * 64 + ni * 16 + li;
        float v = acc[mi][ni][r] + bias[col];
        if (OUT == 0) {
          ((float*)Cout)[(size_t)row * N + col] = v;
        } else {
          int b = row >> 8, tt = row & 255;
          int g = col >> 10, u = col & 1023;
          int idx = ((tt * 4 + (b >> 4)) << 16) | ((u >> 5) << 11) |
                    ((b & 15) << 7) | ((u & 31) << 2) | g;
          ((unsigned short*)Cout)[idx] = f2bf(v);
        }
      }
}

// ---------------- persistent LSTM scan: R12 + split-half bulk pipeline ----------------
// 128 wgs (gb in [0,4), ug in [0,32)): batches [gb*16,+16) x units [ug*32,+32).
// Bulk stage now: coalesced 16B bypass loads (instr i covers contiguous 256B/row-group),
// half A (LDS bytes [0,1K) = ks 0..15) written after vmcnt(4), raw LDS barrier (B loads
// stay in flight), MFMA ks0..15 overlaps B completion; then B half, barrier, MFMA ks16..31.

__global__ __launch_bounds__(256, 1) void k_scan(
    const unsigned short* __restrict__ xgs,   // scan-native (see k_gemm OUT=2)
    const float* __restrict__ Whh,            // [4H][H] f32
    unsigned short* __restrict__ h_pp,        // [2][B][H] bf16 (MALL)
    unsigned short* __restrict__ out_seq,     // [B*T][H] bf16 or null
    float* __restrict__ hT, float* __restrict__ cT,
    const float* __restrict__ h0, const float* __restrict__ c0,
    unsigned* __restrict__ slots) {           // [4][32][32] this layer
  __shared__ __align__(16) unsigned short Wlds[64 * 1024];   // 128 KB
  __shared__ __align__(16) unsigned short Hs[16 * 1024];     // 32 KB (exch aliases head)
  const int tid = threadIdx.x, lane = tid & 63, w = tid >> 6;
  const int gb = blockIdx.x >> 5, ug = blockIdx.x & 31;
  const int li = lane & 15, kq = lane >> 4;
  const int b  = gb * 16 + li;
  const int u0 = ug * 32 + w * 8 + kq;        // acc0's unit
  const int u1 = u0 + 4;                      // acc1's unit

  // ---- publish h0 (read parity 1 at t=0); settles during weight staging
  st_u16_cc(&h_pp[((size_t)B_ + b) * H_ + u0], f2bf(h0[(size_t)b * H_ + u0]));
  st_u16_cc(&h_pp[((size_t)B_ + b) * H_ + u1], f2bf(h0[(size_t)b * H_ + u1]));

  // ---- register A-fragments: rows r0 = w*32+li (16 rows/wave), all K
  bf16x8 afr[32];
  {
    const int r0 = w * 32 + li;               // u_local = r0>>2, gate = r0&3
    const float* wr = Whh + ((size_t)(r0 & 3) * H_ + ug * 32 + (r0 >> 2)) * H_ + kq * 8;
#pragma unroll
    for (int ks = 0; ks < 32; ++ks) {
      const float4 f0 = *(const float4*)(wr + ks * 32);
      const float4 f1 = *(const float4*)(wr + ks * 32 + 4);
      union { ushort4 a[2]; bf16x8 v; } uu_;
      uu_.a[0] = ushort4{f2bf(f0.x), f2bf(f0.y), f2bf(f0.z), f2bf(f0.w)};
      uu_.a[1] = ushort4{f2bf(f1.x), f2bf(f1.y), f2bf(f1.z), f2bf(f1.w)};
      afr[ks] = uu_.v;
    }
  }
  // ---- LDS A tile: rows r = w*32+16+it -> LDS row w*16+it (XOR swizzle by it&7)
  for (int it = 0; it < 16; ++it) {
    const int r = w * 32 + 16 + it;
    const float* wr = Whh + ((size_t)(r & 3) * H_ + ug * 32 + (r >> 2)) * H_;
#pragma unroll
    for (int j = 0; j < 4; ++j) {
      const float4 f = *(const float4*)(wr + lane * 16 + j * 4);
      ushort4 p = ushort4{f2bf(f.x), f2bf(f.y), f2bf(f.z), f2bf(f.w)};
      const int k = lane * 16 + j * 4;
      *(ushort4*)((char*)Wlds + (size_t)(w * 16 + it) * 2048 + ((2 * k) ^ ((it & 7) << 4))) = p;
    }
  }
  float cs0 = c0[(size_t)b * H_ + u0], cs1 = c0[(size_t)b * H_ + u1];
  __syncthreads();                            // drains h0 publishes (per-wave vmcnt0)
  // initial slot=1 to all 32 consumer replicas (wave 3, 32 parallel stores)
  if (w == 3 && lane < 32) {
    st_u32_cc(&slots[gb * 1024 + lane * 32 + ug], 1u);
    asm volatile("s_waitcnt vmcnt(0)" ::: "memory");
  }

  const char* hbase = (const char*)Hs + (size_t)li * 2048;
  const char* wlb   = (const char*)Wlds + (size_t)(w * 16 + li) * 2048;
  const int fxor = (li & 7) << 4;
  const int sb = tid >> 4, seg = tid & 15;
  const int sswz = (sb & 7) << 4;
  char* drow = (char*)Hs + (size_t)sb * 2048;
  unsigned short* exch = Hs;                  // [16][32] u16, 1 KB, phase-separated
  const unsigned* myline = slots + gb * 1024 + ug * 32;   // private poll line

  for (int t = 0; t < T_; ++t) {
    // ---- xv first (HBM latency hides under the poll)
    const size_t xb2 = ((((size_t)t * 4 + gb) << 16) | (ug << 11) | (li << 7) |
                        ((w * 8 + kq) << 2)) * 2;
    const ushort4 xa = *(const ushort4*)((const char*)xgs + xb2);
    const ushort4 xb = *(const ushort4*)((const char*)xgs + xb2 + 32);

    // ---- poll private slot line (wave 0; 64 lanes read one 128B line)
    if (w == 0) {
      const unsigned tgt = (unsigned)(t + 1);
      unsigned v;
      do {
        __builtin_amdgcn_s_sleep(1);
        v = ld_u32_cc(&myline[lane & 31]);
      } while (__any((int)(v < tgt)));
    }
    __syncthreads();

    // ---- split-half bulk: coalesced 16B bypass loads, A half staged, B overlaps MFMA-A
    const char* srcrow = (const char*)(h_pp + (size_t)((t & 1) ^ 1) * (B_ * H_) +
                                       (size_t)(gb * 16 + sb) * H_);
    u32x4 A0 = ld_b128_cc_nw(srcrow +   0 * 256 + seg * 16);
    u32x4 A1 = ld_b128_cc_nw(srcrow +   1 * 256 + seg * 16);
    u32x4 A2 = ld_b128_cc_nw(srcrow +   2 * 256 + seg * 16);
    u32x4 A3 = ld_b128_cc_nw(srcrow +   3 * 256 + seg * 16);
    u32x4 B0 = ld_b128_cc_nw(srcrow + 1024 + 0 * 256 + seg * 16);
    u32x4 B1 = ld_b128_cc_nw(srcrow + 1024 + 1 * 256 + seg * 16);
    u32x4 B2 = ld_b128_cc_nw(srcrow + 1024 + 2 * 256 + seg * 16);
    u32x4 B3 = ld_b128_cc_nw(srcrow + 1024 + 3 * 256 + seg * 16);
    wait_vm4_tie4(A0, A1, A2, A3);            // A half done; B (4) still in flight
    *(u32x4*)(drow + ((0 * 256 + seg * 16) ^ sswz)) = A0;
    *(u32x4*)(drow + ((1 * 256 + seg * 16) ^ sswz)) = A1;
    *(u32x4*)(drow + ((2 * 256 + seg * 16) ^ sswz)) = A2;
    *(u32x4*)(drow + ((3 * 256 + seg * 16) ^ sswz)) = A3;
    lds_barrier();                            // ds drained; B loads cross the barrier

    // ---- MFMA ks 0..15 (A half) — hides B-half completion
    f32x4 a0 = {0.f, 0.f, 0.f, 0.f}, a1 = {0.f, 0.f, 0.f, 0.f};
#pragma unroll
    for (int ks = 0; ks < 16; ++ks) {
      const bf16x8 bb = *(const bf16x8*)(hbase + ((ks * 64 + kq * 16) ^ fxor));
      a0 = __builtin_amdgcn_mfma_f32_16x16x32_bf16(afr[ks], bb, a0, 0, 0, 0);
      const bf16x8 aw = *(const bf16x8*)(wlb + ((ks * 64 + kq * 16) ^ fxor));
      a1 = __builtin_amdgcn_mfma_f32_16x16x32_bf16(aw, bb, a1, 0, 0, 0);
    }

    wait_vm0_tie4(B0, B1, B2, B3);
    *(u32x4*)(drow + ((1024 + 0 * 256 + seg * 16) ^ sswz)) = B0;
    *(u32x4*)(drow + ((1024 + 1 * 256 + seg * 16) ^ sswz)) = B1;
    *(u32x4*)(drow + ((1024 + 2 * 256 + seg * 16) ^ sswz)) = B2;
    *(u32x4*)(drow + ((1024 + 3 * 256 + seg * 16) ^ sswz)) = B3;
    lds_barrier();

    // ---- MFMA ks 16..31 (B half)
#pragma unroll
    for (int ks = 16; ks < 32; ++ks) {
      const bf16x8 bb = *(const bf16x8*)(hbase + ((ks * 64 + kq * 16) ^ fxor));
      a0 = __builtin_amdgcn_mfma_f32_16x16x32_bf16(afr[ks], bb, a0, 0, 0, 0);
      const bf16x8 aw = *(const bf16x8*)(wlb + ((ks * 64 + kq * 16) ^ fxor));
      a1 = __builtin_amdgcn_mfma_f32_16x16x32_bf16(aw, bb, a1, 0, 0, 0);
    }

    // ---- lane-local cell update (2 units x 4 gates)
    float h0v, h1v;
    {
      float gi = a0[0] + bf2f(xa.x), gf = a0[1] + bf2f(xa.y);
      float gg = a0[2] + bf2f(xa.z), go = a0[3] + bf2f(xa.w);
      float ci = sigmf(gf) * cs0 + sigmf(gi) * tanh_f(gg);
      cs0 = ci; h0v = sigmf(go) * tanh_f(ci);
    }
    {
      float gi = a1[0] + bf2f(xb.x), gf = a1[1] + bf2f(xb.y);
      float gg = a1[2] + bf2f(xb.z), go = a1[3] + bf2f(xb.w);
      float ci = sigmf(gf) * cs1 + sigmf(gi) * tanh_f(gg);
      cs1 = ci; h1v = sigmf(go) * tanh_f(ci);
    }
    const unsigned short hb0 = f2bf(h0v), hb1 = f2bf(h1v);

    // ---- LDS transpose for coalesced publish: exch[b_local][u_local]
    __syncthreads();                          // all Hs MFMA reads done
    exch[li * 32 + w * 8 + kq]     = hb0;
    exch[li * 32 + w * 8 + kq + 4] = hb1;
    __syncthreads();

    if (t < T_ - 1) {
      // coalesced publish: 16-thread groups write 64B runs of u32
      const int bl = tid >> 4, j = tid & 15;
      const unsigned pack = (unsigned)exch[bl * 32 + 2 * j] |
                            ((unsigned)exch[bl * 32 + 2 * j + 1] << 16);
      st_u32_cc((unsigned*)&h_pp[((size_t)(t & 1) * B_ + gb * 16 + bl) * H_ + ug * 32 + 2 * j],
                pack);
      asm volatile("s_waitcnt vmcnt(0)" ::: "memory");
      __syncthreads();                        // all publishes ACKed
      // slot = t+2 to all 32 consumer replicas (wave 3, parallel; drain overlaps next poll)
      if (w == 3 && lane < 32) {
        st_u32_cc(&slots[gb * 1024 + lane * 32 + ug], (unsigned)(t + 2));
        asm volatile("s_waitcnt vmcnt(0)" ::: "memory");
      }
    } else {
      hT[(size_t)b * H_ + u0] = h0v; hT[(size_t)b * H_ + u1] = h1v;
      cT[(size_t)b * H_ + u0] = cs0; cT[(size_t)b * H_ + u1] = cs1;
    }

    // ---- out_seq: off critical path, coalesced 16B stores from exch
    if (out_seq && tid < 64) {
      const int bo = tid >> 2, q = tid & 3;
      *(u32x4*)&out_seq[((size_t)(gb * 16 + bo) * T_ + t) * H_ + ug * 32 + 8 * q] =
          *(const u32x4*)&exch[bo * 32 + 8 * q];
    }
  }
}

// ---------------- launcher ----------------

extern "C" void kernel_launch(void* const* d_in, const int* in_sizes, int n_in,
                              void* d_out, int out_size, void* d_ws, size_t ws_size,
                              hipStream_t stream) {
  const float* seq  = (const float*)d_in[0];
  const float* Wi2h = (const float*)d_in[1];
  const float* bi2h = (const float*)d_in[2];
  const float* Wih  = (const float*)d_in[3];
  const float* Whh  = (const float*)d_in[4];
  const float* bih  = (const float*)d_in[5];
  const float* bhh  = (const float*)d_in[6];
  const float* Wh2o = (const float*)d_in[7];
  const float* bh2o = (const float*)d_in[8];
  const float* h0   = (const float*)d_in[9];
  const float* c0   = (const float*)d_in[10];
  float* outF = (float*)d_out;

  size_t off = 0;
  auto nb = [&](size_t bytes) { size_t r = off; off += (bytes + 255) & ~(size_t)255; return r; };
  unsigned short* xbf   = (unsigned short*)((char*)d_ws + nb((size_t)B_ * T_ * H_ * 2));
  unsigned short* seqA  = (unsigned short*)((char*)d_ws + nb((size_t)B_ * T_ * H_ * 2));
  unsigned short* xgs   = (unsigned short*)((char*)d_ws + nb((size_t)B_ * T_ * 4 * H_ * 2));
  unsigned short* Wihb  = (unsigned short*)((char*)d_ws + nb((size_t)L_ * 4 * H_ * H_ * 2));
  unsigned short* Wh2ob = (unsigned short*)((char*)d_ws + nb((size_t)AS_ * H_ * 2));
  unsigned short* Wt    = (unsigned short*)((char*)d_ws + nb((size_t)AS_ * H_ * 2));
  float*          bsum  = (float*)((char*)d_ws + nb((size_t)L_ * 4 * H_ * 4));
  unsigned short* h_pp  = (unsigned short*)((char*)d_ws + nb((size_t)2 * B_ * H_ * 2));  // 256KB
  unsigned*       slt   = (unsigned*)((char*)d_ws + nb((size_t)L_ * 4 * 32 * 32 * 4));   // 48KB
  (void)ws_size; (void)in_sizes; (void)n_in; (void)out_size;

  const int WLAYER = 4 * H_ * H_;

  k_zero<<<(L_ * 4096 + 255) / 256, 256, 0, stream>>>(slt, L_ * 4096);
  k_wt_i2h<<<(AS_ * H_ + 255) / 256, 256, 0, stream>>>(Wi2h, bi2h, Wt);
  k_f2b<<<(L_ * WLAYER + 255) / 256, 256, 0, stream>>>(Wih, Wihb, L_ * WLAYER);
  k_f2b<<<(AS_ * H_ + 255) / 256, 256, 0, stream>>>(Wh2o, Wh2ob, AS_ * H_);
  k_bias<<<(L_ * 4 * H_ + 255) / 256, 256, 0, stream>>>(bih, bhh, bsum, L_ * 4 * H_);
  k_gather<<<B_ * T_, 128, 0, stream>>>(seq, Wt, xbf);

  // out = x @ W_h2O^T + b  (faithful to reference bug: uses x, not LSTM output)
  k_gemm<0><<<dim3(B_ * T_ / 128, AS_ / 128), 256, 0, stream>>>(
      xbf, Wh2ob, bh2o, (void*)outF, B_ * T_, AS_, H_);

  float* hT_base = outF + (size_t)B_ * T_ * AS_;
  float* cT_base = hT_base + (size_t)L_ * B_ * H_;

  for (int l = 0; l < L_; ++l) {
    const unsigned short* Ain = (l == 0) ? xbf : (l == 1) ? seqA : xbf;
    unsigned short* oseq = (l == 0) ? seqA : (l == 1) ? xbf : nullptr;
    k_gemm<2><<<dim3(B_ * T_ / 128, 4 * H_ / 128), 256, 0, stream>>>(
        Ain, Wihb + (size_t)l * WLAYER, bsum + (size_t)l * 4 * H_, (void*)xgs,
        B_ * T_, 4 * H_, H_);
    k_scan<<<128, 256, 0, stream>>>(
        xgs, Whh + (size_t)l * WLAYER, h_pp, oseq,
        hT_base + (size_t)l * B_ * H_, cT_base + (size_t)l * B_ * H_,
        h0 + (size_t)l * B_ * H_, c0 + (size_t)l * B_ * H_,
        slt + (size_t)l * 4096);
  }
}

// Round 14
// 3488.366 us; speedup vs baseline: 2.7678x; 1.0596x over previous
//
#include <hip/hip_runtime.h>
#include <stdint.h>
#include <stddef.h>

#define B_  64
#define T_  256
#define H_  1024
#define AS_ 128
#define L_  3

typedef __attribute__((ext_vector_type(8))) short bf16x8;
typedef __attribute__((ext_vector_type(4))) float f32x4;
typedef __attribute__((ext_vector_type(4))) unsigned u32x4;

__device__ __forceinline__ unsigned short f2bf(float f) {
  union { float f; unsigned u; } x; x.f = f;
  unsigned r = x.u + 0x7fffu + ((x.u >> 16) & 1u);   // RNE
  return (unsigned short)(r >> 16);
}
__device__ __forceinline__ float bf2f(unsigned short s) {
  union { unsigned u; float f; } x; x.u = ((unsigned)s) << 16; return x.f;
}
__device__ __forceinline__ float sigmf(float x) { return 1.0f / (1.0f + __expf(-x)); }
__device__ __forceinline__ float tanh_f(float x) {
  x = fminf(fmaxf(x, -15.0f), 15.0f);
  float e = __expf(2.0f * x);
  return (e - 1.0f) / (e + 1.0f);
}

// ---- device-coherent (MALL) accessors: relaxed agent atomics — proven R2..R13 ----
__device__ __forceinline__ void st_u16_cc(unsigned short* p, unsigned short v) {
  __hip_atomic_store(p, v, __ATOMIC_RELAXED, __HIP_MEMORY_SCOPE_AGENT);
}
__device__ __forceinline__ void st_u32_cc(unsigned* p, unsigned v) {
  __hip_atomic_store(p, v, __ATOMIC_RELAXED, __HIP_MEMORY_SCOPE_AGENT);
}
__device__ __forceinline__ unsigned ld_u32_cc(const unsigned* p) {
  return __hip_atomic_load(p, __ATOMIC_RELAXED, __HIP_MEMORY_SCOPE_AGENT);
}
// full-bypass 16B load/store, no wait — proven R11/R13
__device__ __forceinline__ u32x4 ld_b128_cc_nw(const void* p) {
  u32x4 r;
  asm volatile("global_load_dwordx4 %0, %1, off sc0 sc1" : "=v"(r) : "v"(p));
  return r;
}
__device__ __forceinline__ void st_b128_cc_nw(void* p, u32x4 v) {
  asm volatile("global_store_dwordx4 %0, %1, off sc0 sc1" :: "v"(p), "v"(v) : "memory");
}
// counted waits with tied operands (rule #18)
__device__ __forceinline__ void wait_vm4_tie4(u32x4& a, u32x4& b, u32x4& c, u32x4& d) {
  asm volatile("s_waitcnt vmcnt(4)"
               : "+v"(a), "+v"(b), "+v"(c), "+v"(d) :: "memory");
  __builtin_amdgcn_sched_barrier(0);
}
__device__ __forceinline__ void wait_vm0_tie4(u32x4& a, u32x4& b, u32x4& c, u32x4& d) {
  asm volatile("s_waitcnt vmcnt(0)"
               : "+v"(a), "+v"(b), "+v"(c), "+v"(d) :: "memory");
  __builtin_amdgcn_sched_barrier(0);
}
// LDS-only barrier: keeps outstanding global loads in flight across it
__device__ __forceinline__ void lds_barrier() {
  __builtin_amdgcn_sched_barrier(0);
  asm volatile("s_waitcnt lgkmcnt(0)" ::: "memory");
  __builtin_amdgcn_sched_barrier(0);
  __builtin_amdgcn_s_barrier();
  __builtin_amdgcn_sched_barrier(0);
}

// ---------------- tiny utility kernels ----------------

__global__ void k_zero(unsigned* p, int n) {
  int i = blockIdx.x * 256 + threadIdx.x;
  if (i < n) st_u32_cc(p + i, 0u);
}

__global__ void k_wt_i2h(const float* __restrict__ W, const float* __restrict__ b,
                         unsigned short* __restrict__ Wt) {
  int id = blockIdx.x * 256 + threadIdx.x;
  if (id >= AS_ * H_) return;
  int a = id >> 10, h = id & 1023;
  Wt[id] = f2bf(W[h * AS_ + a] + b[h]);
}

__global__ void k_f2b(const float* __restrict__ s, unsigned short* __restrict__ d, int n) {
  int i = blockIdx.x * 256 + threadIdx.x;
  if (i < n) d[i] = f2bf(s[i]);
}

__global__ void k_bias(const float* __restrict__ bi, const float* __restrict__ bh,
                       float* __restrict__ o, int n) {
  int i = blockIdx.x * 256 + threadIdx.x;
  if (i < n) o[i] = bi[i] + bh[i];
}

__global__ __launch_bounds__(128) void k_gather(const float* __restrict__ seq,
                                                const unsigned short* __restrict__ Wt,
                                                unsigned short* __restrict__ xbf) {
  __shared__ int sidx;
  const int bt = blockIdx.x, tid = threadIdx.x;
  if (seq[(size_t)bt * AS_ + tid] > 0.5f) sidx = tid;
  __syncthreads();
  const uint4* s = (const uint4*)(Wt + (size_t)sidx * H_);
  uint4* d = (uint4*)(xbf + (size_t)bt * H_);
  d[tid] = s[tid];
}

// ---------------- shared MFMA GEMM tile body ----------------
// OUT==0: float row-major [M][N].  OUT==2: bf16 scan-native (uu=32) layout.
// AMAJ==0: A row = b*256+t (b-major).  AMAJ==1: A row = t*64+b (t-major).

__device__ __forceinline__ void gld16(const void* g, void* l) {
  __builtin_amdgcn_global_load_lds((const __attribute__((address_space(1))) unsigned int*)g,
                                   (__attribute__((address_space(3))) unsigned int*)l,
                                   16, 0, 0);
}

template <int OUT, int AMAJ>
__device__ __forceinline__ void gemm_tile(const unsigned short* __restrict__ A,
                                          const unsigned short* __restrict__ Bm,
                                          const float* __restrict__ bias,
                                          void* __restrict__ Cout,
                                          int m0, int n0, int K, int N, int tid,
                                          unsigned short* As, unsigned short* Bs) {
  const int lane = tid & 63, wv = tid >> 6;
  const int wr = wv >> 1, wc = wv & 1;
  const int kg = lane >> 4, li = lane & 15;
  f32x4 acc[4][4] = {};

  for (int k0 = 0; k0 < K; k0 += 32) {
    for (int i = 0; i < 2; ++i) {
      int c0 = i * 256 + wv * 64;
      int cid = c0 + lane;
      int row = cid >> 2, lc = cid & 3;
      int sc = lc ^ ((row >> 1) & 3);
      gld16(A + (size_t)(m0 + row) * K + k0 + sc * 8, (char*)As + (size_t)c0 * 16);
      gld16(Bm + (size_t)(n0 + row) * K + k0 + sc * 8, (char*)Bs + (size_t)c0 * 16);
    }
    __syncthreads();
    bf16x8 af[4], bfm[4];
#pragma unroll
    for (int mi = 0; mi < 4; ++mi) {
      int row = wr * 64 + mi * 16 + li;
      int pc = kg ^ ((row >> 1) & 3);
      af[mi] = *(const bf16x8*)((const char*)As + row * 64 + pc * 16);
    }
#pragma unroll
    for (int ni = 0; ni < 4; ++ni) {
      int row = wc * 64 + ni * 16 + li;
      int pc = kg ^ ((row >> 1) & 3);
      bfm[ni] = *(const bf16x8*)((const char*)Bs + row * 64 + pc * 16);
    }
#pragma unroll
    for (int mi = 0; mi < 4; ++mi)
#pragma unroll
      for (int ni = 0; ni < 4; ++ni)
        acc[mi][ni] = __builtin_amdgcn_mfma_f32_16x16x32_bf16(af[mi], bfm[ni], acc[mi][ni], 0, 0, 0);
    __syncthreads();
  }

#pragma unroll
  for (int mi = 0; mi < 4; ++mi)
#pragma unroll
    for (int ni = 0; ni < 4; ++ni)
#pragma unroll
      for (int r = 0; r < 4; ++r) {
        int row = m0 + wr * 64 + mi * 16 + kg * 4 + r;
        int col = n0 + wc * 64 + ni * 16 + li;
        float v = acc[mi][ni][r] + bias[col];
        if (OUT == 0) {
          ((float*)Cout)[(size_t)row * N + col] = v;
        } else {
          int b, tt;
          if (AMAJ == 0) { b = row >> 8; tt = row & 255; }
          else           { tt = row >> 6; b = row & 63; }
          int g = col >> 10, u = col & 1023;
          int idx = ((tt * 4 + (b >> 4)) << 16) | ((u >> 5) << 11) |
                    ((b & 15) << 7) | ((u & 31) << 2) | g;
          ((unsigned short*)Cout)[idx] = f2bf(v);
        }
      }
}

template <int OUT, int AMAJ>
__global__ __launch_bounds__(256) void k_gemm(const unsigned short* __restrict__ A,
                                              const unsigned short* __restrict__ Bm,
                                              const float* __restrict__ bias,
                                              void* __restrict__ Cout,
                                              int M, int N, int K) {
  __shared__ __align__(16) unsigned short As[128 * 32];
  __shared__ __align__(16) unsigned short Bs[128 * 32];
  gemm_tile<OUT, AMAJ>(A, Bm, bias, Cout, blockIdx.x * 128, blockIdx.y * 128,
                       K, N, threadIdx.x, As, Bs);
}

// ---------------- fused: persistent scan (wgs 0..127) + next-layer GEMM workers (128..255) ----
// Scan = R13 structure. out_seq is t-major [T][B][H], bypass-written BEFORE the slot
// drain, so slot value t+2 certifies out_seq rows <= t visible at MALL. GEMM worker
// tile mt covers A rows t in {2mt, 2mt+1}; poll all 128 slots >= 2mt+3 also proves
// scan consumed xgs[<=2mt+1] -> in-place xgs overwrite is safe. 256 wgs at 160KB LDS
// = 1 wg/CU on 256 CUs -> all co-resident (R2 precedent), no dispatch-order deadlock.

__global__ __launch_bounds__(256, 1) void k_fused(
    const unsigned short* __restrict__ xgs,   // scan input (scan-native)
    const float* __restrict__ Whh,            // [4H][H] f32, layer l
    unsigned short* __restrict__ h_pp,        // [2][B][H] bf16 (MALL)
    unsigned short* __restrict__ out_seq,     // [T][B][H] bf16 t-major, or null; also gw Ain
    float* __restrict__ hT, float* __restrict__ cT,
    const float* __restrict__ h0, const float* __restrict__ c0,
    unsigned* __restrict__ slots,             // [4][32][32] layer l
    const unsigned short* __restrict__ WihbN, // layer l+1 W_ih bf16 (gw)
    const float* __restrict__ bsumN,          // layer l+1 bias (gw)
    unsigned short* __restrict__ xgs_out) {   // gw output (= xgs, in-place)
  __shared__ __align__(16) unsigned short Wlds[64 * 1024];   // 128 KB
  __shared__ __align__(16) unsigned short Hs[16 * 1024];     // 32 KB
  const int tid = threadIdx.x, lane = tid & 63, w = tid >> 6;
  const int wg = blockIdx.x;

  if (wg >= 128) {
    // ---------------- GEMM worker: 32 tiles, t-gated ----------------
    const int Wp = wg - 128;
    unsigned short* As = Wlds;
    unsigned short* Bs = Wlds + 4096;
    const int pline = (Wp & 31) * 32;
    for (int k = 0; k < 32; ++k) {
      const int gidx = Wp + k * 128;          // mt ascending per worker
      const int mt = gidx >> 5, nt = gidx & 31;
      const unsigned tgt = (unsigned)(2 * mt + 3);
      if (w == 0) {                           // poll 128 slots: gb=lane>>4, 2 producers/lane
        const unsigned* base = slots + (lane >> 4) * 1024 + pline + (lane & 15);
        unsigned v0, v1;
        do {
          __builtin_amdgcn_s_sleep(4);
          v0 = ld_u32_cc(base);
          v1 = ld_u32_cc(base + 16);
        } while (__any((int)((v0 < tgt) | (v1 < tgt))));
      }
      __syncthreads();
      gemm_tile<2, 1>(out_seq, WihbN, bsumN, (void*)xgs_out,
                      mt * 128, nt * 128, H_, 4 * H_, tid, As, Bs);
    }
    return;
  }

  // ---------------- scan path (R13, out_seq t-major + pre-drain bypass stores) ----------------
  const int gb = wg >> 5, ug = wg & 31;
  const int li = lane & 15, kq = lane >> 4;
  const int b  = gb * 16 + li;
  const int u0 = ug * 32 + w * 8 + kq;
  const int u1 = u0 + 4;

  st_u16_cc(&h_pp[((size_t)B_ + b) * H_ + u0], f2bf(h0[(size_t)b * H_ + u0]));
  st_u16_cc(&h_pp[((size_t)B_ + b) * H_ + u1], f2bf(h0[(size_t)b * H_ + u1]));

  bf16x8 afr[32];
  {
    const int r0 = w * 32 + li;
    const float* wr = Whh + ((size_t)(r0 & 3) * H_ + ug * 32 + (r0 >> 2)) * H_ + kq * 8;
#pragma unroll
    for (int ks = 0; ks < 32; ++ks) {
      const float4 f0 = *(const float4*)(wr + ks * 32);
      const float4 f1 = *(const float4*)(wr + ks * 32 + 4);
      union { ushort4 a[2]; bf16x8 v; } uu_;
      uu_.a[0] = ushort4{f2bf(f0.x), f2bf(f0.y), f2bf(f0.z), f2bf(f0.w)};
      uu_.a[1] = ushort4{f2bf(f1.x), f2bf(f1.y), f2bf(f1.z), f2bf(f1.w)};
      afr[ks] = uu_.v;
    }
  }
  for (int it = 0; it < 16; ++it) {
    const int r = w * 32 + 16 + it;
    const float* wr = Whh + ((size_t)(r & 3) * H_ + ug * 32 + (r >> 2)) * H_;
#pragma unroll
    for (int j = 0; j < 4; ++j) {
      const float4 f = *(const float4*)(wr + lane * 16 + j * 4);
      ushort4 p = ushort4{f2bf(f.x), f2bf(f.y), f2bf(f.z), f2bf(f.w)};
      const int k = lane * 16 + j * 4;
      *(ushort4*)((char*)Wlds + (size_t)(w * 16 + it) * 2048 + ((2 * k) ^ ((it & 7) << 4))) = p;
    }
  }
  float cs0 = c0[(size_t)b * H_ + u0], cs1 = c0[(size_t)b * H_ + u1];
  __syncthreads();
  if (w == 3 && lane < 32) {
    st_u32_cc(&slots[gb * 1024 + lane * 32 + ug], 1u);
    asm volatile("s_waitcnt vmcnt(0)" ::: "memory");
  }

  const char* hbase = (const char*)Hs + (size_t)li * 2048;
  const char* wlb   = (const char*)Wlds + (size_t)(w * 16 + li) * 2048;
  const int fxor = (li & 7) << 4;
  const int sb = tid >> 4, seg = tid & 15;
  const int sswz = (sb & 7) << 4;
  char* drow = (char*)Hs + (size_t)sb * 2048;
  unsigned short* exch = Hs;                  // [16][32] u16, phase-separated
  const unsigned* myline = slots + gb * 1024 + ug * 32;

  for (int t = 0; t < T_; ++t) {
    const size_t xb2 = ((((size_t)t * 4 + gb) << 16) | (ug << 11) | (li << 7) |
                        ((w * 8 + kq) << 2)) * 2;
    const ushort4 xa = *(const ushort4*)((const char*)xgs + xb2);
    const ushort4 xb = *(const ushort4*)((const char*)xgs + xb2 + 32);

    if (w == 0) {
      const unsigned tgt = (unsigned)(t + 1);
      unsigned v;
      do {
        __builtin_amdgcn_s_sleep(1);
        v = ld_u32_cc(&myline[lane & 31]);
      } while (__any((int)(v < tgt)));
    }
    __syncthreads();

    // split-half bulk: coalesced 16B bypass loads, B half overlaps MFMA-A
    const char* srcrow = (const char*)(h_pp + (size_t)((t & 1) ^ 1) * (B_ * H_) +
                                       (size_t)(gb * 16 + sb) * H_);
    u32x4 A0 = ld_b128_cc_nw(srcrow +   0 * 256 + seg * 16);
    u32x4 A1 = ld_b128_cc_nw(srcrow +   1 * 256 + seg * 16);
    u32x4 A2 = ld_b128_cc_nw(srcrow +   2 * 256 + seg * 16);
    u32x4 A3 = ld_b128_cc_nw(srcrow +   3 * 256 + seg * 16);
    u32x4 B0 = ld_b128_cc_nw(srcrow + 1024 + 0 * 256 + seg * 16);
    u32x4 B1 = ld_b128_cc_nw(srcrow + 1024 + 1 * 256 + seg * 16);
    u32x4 B2 = ld_b128_cc_nw(srcrow + 1024 + 2 * 256 + seg * 16);
    u32x4 B3 = ld_b128_cc_nw(srcrow + 1024 + 3 * 256 + seg * 16);
    wait_vm4_tie4(A0, A1, A2, A3);
    *(u32x4*)(drow + ((0 * 256 + seg * 16) ^ sswz)) = A0;
    *(u32x4*)(drow + ((1 * 256 + seg * 16) ^ sswz)) = A1;
    *(u32x4*)(drow + ((2 * 256 + seg * 16) ^ sswz)) = A2;
    *(u32x4*)(drow + ((3 * 256 + seg * 16) ^ sswz)) = A3;
    lds_barrier();

    f32x4 a0 = {0.f, 0.f, 0.f, 0.f}, a1 = {0.f, 0.f, 0.f, 0.f};
#pragma unroll
    for (int ks = 0; ks < 16; ++ks) {
      const bf16x8 bb = *(const bf16x8*)(hbase + ((ks * 64 + kq * 16) ^ fxor));
      a0 = __builtin_amdgcn_mfma_f32_16x16x32_bf16(afr[ks], bb, a0, 0, 0, 0);
      const bf16x8 aw = *(const bf16x8*)(wlb + ((ks * 64 + kq * 16) ^ fxor));
      a1 = __builtin_amdgcn_mfma_f32_16x16x32_bf16(aw, bb, a1, 0, 0, 0);
    }

    wait_vm0_tie4(B0, B1, B2, B3);
    *(u32x4*)(drow + ((1024 + 0 * 256 + seg * 16) ^ sswz)) = B0;
    *(u32x4*)(drow + ((1024 + 1 * 256 + seg * 16) ^ sswz)) = B1;
    *(u32x4*)(drow + ((1024 + 2 * 256 + seg * 16) ^ sswz)) = B2;
    *(u32x4*)(drow + ((1024 + 3 * 256 + seg * 16) ^ sswz)) = B3;
    lds_barrier();

#pragma unroll
    for (int ks = 16; ks < 32; ++ks) {
      const bf16x8 bb = *(const bf16x8*)(hbase + ((ks * 64 + kq * 16) ^ fxor));
      a0 = __builtin_amdgcn_mfma_f32_16x16x32_bf16(afr[ks], bb, a0, 0, 0, 0);
      const bf16x8 aw = *(const bf16x8*)(wlb + ((ks * 64 + kq * 16) ^ fxor));
      a1 = __builtin_amdgcn_mfma_f32_16x16x32_bf16(aw, bb, a1, 0, 0, 0);
    }

    float h0v, h1v;
    {
      float gi = a0[0] + bf2f(xa.x), gf = a0[1] + bf2f(xa.y);
      float gg = a0[2] + bf2f(xa.z), go = a0[3] + bf2f(xa.w);
      float ci = sigmf(gf) * cs0 + sigmf(gi) * tanh_f(gg);
      cs0 = ci; h0v = sigmf(go) * tanh_f(ci);
    }
    {
      float gi = a1[0] + bf2f(xb.x), gf = a1[1] + bf2f(xb.y);
      float gg = a1[2] + bf2f(xb.z), go = a1[3] + bf2f(xb.w);
      float ci = sigmf(gf) * cs1 + sigmf(gi) * tanh_f(gg);
      cs1 = ci; h1v = sigmf(go) * tanh_f(ci);
    }
    const unsigned short hb0 = f2bf(h0v), hb1 = f2bf(h1v);

    __syncthreads();                          // all Hs MFMA reads done
    exch[li * 32 + w * 8 + kq]     = hb0;
    exch[li * 32 + w * 8 + kq + 4] = hb1;
    __syncthreads();

    // publish h_pp (t<T-1) and out_seq (always, t-major, bypass) then ONE drain
    if (t < T_ - 1) {
      const int bl = tid >> 4, j = tid & 15;
      const unsigned pack = (unsigned)exch[bl * 32 + 2 * j] |
                            ((unsigned)exch[bl * 32 + 2 * j + 1] << 16);
      st_u32_cc((unsigned*)&h_pp[((size_t)(t & 1) * B_ + gb * 16 + bl) * H_ + ug * 32 + 2 * j],
                pack);
    } else {
      hT[(size_t)b * H_ + u0] = h0v; hT[(size_t)b * H_ + u1] = h1v;
      cT[(size_t)b * H_ + u0] = cs0; cT[(size_t)b * H_ + u1] = cs1;
    }
    if (out_seq && tid < 64) {
      const int bo = tid >> 2, q = tid & 3;
      st_b128_cc_nw(&out_seq[((size_t)t * B_ + gb * 16 + bo) * H_ + ug * 32 + 8 * q],
                    *(const u32x4*)&exch[bo * 32 + 8 * q]);
    }
    asm volatile("s_waitcnt vmcnt(0)" ::: "memory");
    __syncthreads();                          // all publishes + out_seq ACKed
    if (w == 3 && lane < 32) {                // slot t+2 every step (incl. final 257)
      st_u32_cc(&slots[gb * 1024 + lane * 32 + ug], (unsigned)(t + 2));
      asm volatile("s_waitcnt vmcnt(0)" ::: "memory");
    }
  }
}

// ---------------- launcher ----------------

extern "C" void kernel_launch(void* const* d_in, const int* in_sizes, int n_in,
                              void* d_out, int out_size, void* d_ws, size_t ws_size,
                              hipStream_t stream) {
  const float* seq  = (const float*)d_in[0];
  const float* Wi2h = (const float*)d_in[1];
  const float* bi2h = (const float*)d_in[2];
  const float* Wih  = (const float*)d_in[3];
  const float* Whh  = (const float*)d_in[4];
  const float* bih  = (const float*)d_in[5];
  const float* bhh  = (const float*)d_in[6];
  const float* Wh2o = (const float*)d_in[7];
  const float* bh2o = (const float*)d_in[8];
  const float* h0   = (const float*)d_in[9];
  const float* c0   = (const float*)d_in[10];
  float* outF = (float*)d_out;

  size_t off = 0;
  auto nb = [&](size_t bytes) { size_t r = off; off += (bytes + 255) & ~(size_t)255; return r; };
  unsigned short* xbf   = (unsigned short*)((char*)d_ws + nb((size_t)B_ * T_ * H_ * 2));
  unsigned short* seqA  = (unsigned short*)((char*)d_ws + nb((size_t)B_ * T_ * H_ * 2));
  unsigned short* xgs   = (unsigned short*)((char*)d_ws + nb((size_t)B_ * T_ * 4 * H_ * 2));
  unsigned short* Wihb  = (unsigned short*)((char*)d_ws + nb((size_t)L_ * 4 * H_ * H_ * 2));
  unsigned short* Wh2ob = (unsigned short*)((char*)d_ws + nb((size_t)AS_ * H_ * 2));
  unsigned short* Wt    = (unsigned short*)((char*)d_ws + nb((size_t)AS_ * H_ * 2));
  float*          bsum  = (float*)((char*)d_ws + nb((size_t)L_ * 4 * H_ * 4));
  unsigned short* h_pp  = (unsigned short*)((char*)d_ws + nb((size_t)2 * B_ * H_ * 2));
  unsigned*       slt   = (unsigned*)((char*)d_ws + nb((size_t)L_ * 4 * 32 * 32 * 4));
  (void)ws_size; (void)in_sizes; (void)n_in; (void)out_size;

  const int WLAYER = 4 * H_ * H_;

  k_zero<<<(L_ * 4096 + 255) / 256, 256, 0, stream>>>(slt, L_ * 4096);
  k_wt_i2h<<<(AS_ * H_ + 255) / 256, 256, 0, stream>>>(Wi2h, bi2h, Wt);
  k_f2b<<<(L_ * WLAYER + 255) / 256, 256, 0, stream>>>(Wih, Wihb, L_ * WLAYER);
  k_f2b<<<(AS_ * H_ + 255) / 256, 256, 0, stream>>>(Wh2o, Wh2ob, AS_ * H_);
  k_bias<<<(L_ * 4 * H_ + 255) / 256, 256, 0, stream>>>(bih, bhh, bsum, L_ * 4 * H_);
  k_gather<<<B_ * T_, 128, 0, stream>>>(seq, Wt, xbf);

  // out = x @ W_h2O^T + b  (faithful to reference bug: uses x, not LSTM output)
  k_gemm<0, 0><<<dim3(B_ * T_ / 128, AS_ / 128), 256, 0, stream>>>(
      xbf, Wh2ob, bh2o, (void*)outF, B_ * T_, AS_, H_);

  // layer-0 xg GEMM (A = xbf, b-major)
  k_gemm<2, 0><<<dim3(B_ * T_ / 128, 4 * H_ / 128), 256, 0, stream>>>(
      xbf, Wihb, bsum, (void*)xgs, B_ * T_, 4 * H_, H_);

  float* hT_base = outF + (size_t)B_ * T_ * AS_;
  float* cT_base = hT_base + (size_t)L_ * B_ * H_;

  // K1: scan(0) || gemm-worker(1):  out_seq -> seqA (t-major); gw reads seqA, writes xgs
  k_fused<<<256, 256, 0, stream>>>(
      xgs, Whh, h_pp, seqA,
      hT_base, cT_base, h0, c0, slt,
      Wihb + (size_t)1 * WLAYER, bsum + (size_t)1 * 4 * H_, xgs);

  // K2: scan(1) || gemm-worker(2):  out_seq -> xbf (t-major); gw reads xbf, writes xgs
  k_fused<<<256, 256, 0, stream>>>(
      xgs, Whh + (size_t)1 * WLAYER, h_pp, xbf,
      hT_base + (size_t)B_ * H_, cT_base + (size_t)B_ * H_,
      h0 + (size_t)B_ * H_, c0 + (size_t)B_ * H_, slt + (size_t)4096,
      Wihb + (size_t)2 * WLAYER, bsum + (size_t)2 * 4 * H_, xgs);

  // K3: scan(2) only (grid 128, no out_seq, no gw)
  k_fused<<<128, 256, 0, stream>>>(
      xgs, Whh + (size_t)2 * WLAYER, h_pp, nullptr,
      hT_base + (size_t)2 * B_ * H_, cT_base + (size_t)2 * B_ * H_,
      h0 + (size_t)2 * B_ * H_, c0 + (size_t)2 * B_ * H_, slt + (size_t)2 * 4096,
      nullptr, nullptr, nullptr);
}